// Round 3
// baseline (1096.325 us; speedup 1.0000x reference)
//
#include <hip/hip_runtime.h>
#include <hip/hip_bf16.h>
#include <hip/hip_fp16.h>

// GGM encode, decomposed (inputs/outputs fp32; internal MFMA in fp16, fp32 accum):
//   agg[v] = deg(v)*(U1 h_v + c_k) + U2*S_h[v] + U3*S_e[v]
//   S_h[v] = sum_{e: dst=v} h[src_e]   (per round, CSR gather, fp32 acc -> fp16)
//   S_e[v] = sum_{e: dst=v} e_e        (once)
//   c_k    = U4 cond + U_b             (once, fp32 exact)
// then GRU: gi = agg@Wih^T + bih, gh = h@Whh^T + bhh, fused elementwise in fp32.
// fp16 (10-bit mantissa) vs bf16 (7-bit): 8x lower rounding noise, same MFMA rate.

#define D_NODE 128
#define D_EDGE 64
#define D_IN   322
#define D_IN_P 336   // padded fp16 row stride for U_W (16B-aligned fragment loads)
#define GRU3   384

typedef _Float16 f16x8 __attribute__((ext_vector_type(8)));
typedef float    f32x4 __attribute__((ext_vector_type(4)));
typedef unsigned short u16x8 __attribute__((ext_vector_type(8)));

__device__ __forceinline__ f16x8 as_f16x8(u16x8 v) { return __builtin_bit_cast(f16x8, v); }
__device__ __forceinline__ f16x8 cvt8(const float* __restrict__ p) {
    const f32x4 u = *(const f32x4*)p;
    const f32x4 v = *(const f32x4*)(p + 4);
    f16x8 r;
    r[0] = (_Float16)u[0]; r[1] = (_Float16)u[1]; r[2] = (_Float16)u[2]; r[3] = (_Float16)u[3];
    r[4] = (_Float16)v[0]; r[5] = (_Float16)v[1]; r[6] = (_Float16)v[2]; r[7] = (_Float16)v[3];
    return r;
}
__device__ __forceinline__ float sigm_(float x) { return 1.f / (1.f + __expf(-x)); }
__device__ __forceinline__ float tanh_(float x) { return 1.f - 2.f / (__expf(2.f * x) + 1.f); }

// ---------------- CSR build ----------------
__global__ void hist_k(const int* __restrict__ dst, int* __restrict__ cnt, int E) {
    int t = blockIdx.x * 256 + threadIdx.x;
    if (t < E) atomicAdd(&cnt[dst[t]], 1);
}

__global__ __launch_bounds__(1024) void scan_k(const int* __restrict__ cnt, int* __restrict__ row_ptr,
                                               int* __restrict__ cursor, int N) {
    __shared__ int sums[1024];
    const int t = threadIdx.x;
    const int chunk = (N + 1023) / 1024;
    const int s0 = min(t * chunk, N);
    const int s1 = min(s0 + chunk, N);
    int sum = 0;
    for (int i = s0; i < s1; ++i) sum += cnt[i];
    sums[t] = sum;
    __syncthreads();
    for (int off = 1; off < 1024; off <<= 1) {
        int v = (t >= off) ? sums[t - off] : 0;
        __syncthreads();
        sums[t] += v;
        __syncthreads();
    }
    int run = (t == 0) ? 0 : sums[t - 1];
    for (int i = s0; i < s1; ++i) {
        row_ptr[i] = run;
        cursor[i] = run;
        run += cnt[i];
    }
    if (t == 1023) row_ptr[N] = sums[1023];
}

__global__ void scatter_k(const int* __restrict__ src, const int* __restrict__ dst,
                          int* __restrict__ cursor, int* __restrict__ csr_src,
                          int* __restrict__ csr_eid, int E) {
    int t = blockIdx.x * 256 + threadIdx.x;
    if (t < E) {
        int d = dst[t];
        int pos = atomicAdd(&cursor[d], 1);
        csr_src[pos] = src[t];
        csr_eid[pos] = t;
    }
}

// ---------------- weight converts (fp32 -> fp16, once per launch) ----------------
// U_W: [384][322] fp32 -> [384][336] fp16 (padded)
__global__ __launch_bounds__(384) void cvt_uw_k(const float* __restrict__ in, _Float16* __restrict__ out) {
    const int row = blockIdx.x;
    const int t = threadIdx.x;
    if (t < D_IN_P)
        out[row * D_IN_P + t] = (_Float16)(t < D_IN ? in[row * D_IN + t] : 0.f);
}

__global__ void cvt_f32_k(const float* __restrict__ in, _Float16* __restrict__ out, int n) {
    int t = blockIdx.x * 256 + threadIdx.x;
    if (t < n) out[t] = (_Float16)in[t];
}

// ---------------- c_k = U4*cond + U_b (fp32 exact) ----------------
__global__ void compute_c_k(const float* __restrict__ UW, const float* __restrict__ Ub,
                            const float* __restrict__ cond, float* __restrict__ cvec) {
    int t = threadIdx.x;
    if (t < 3 * D_NODE) {
        int k = t >> 7, i = t & 127;
        const float* u = UW + (size_t)k * D_NODE * D_IN + (size_t)i * D_IN + 320;
        cvec[t] = u[0] * cond[0] + u[1] * cond[1] + Ub[k * D_NODE + i];
    }
}

// ---------------- segment sums (CSR gather, wave per node; fp32 acc -> fp16) ----------------
__global__ __launch_bounds__(256) void gather_e_k(const float* __restrict__ e,
                                                  const int* __restrict__ row_ptr,
                                                  const int* __restrict__ csr_eid,
                                                  _Float16* __restrict__ S_e, int N) {
    const int wave = threadIdx.x >> 6, lane = threadIdx.x & 63;
    const int n = blockIdx.x * 4 + wave;
    if (n >= N) return;
    const int p1 = row_ptr[n + 1];
    float a0 = 0.f;
    for (int p = row_ptr[n]; p < p1; ++p) {
        const int eid = csr_eid[p];
        a0 += e[(size_t)eid * D_EDGE + lane];
    }
    S_e[(size_t)n * D_EDGE + lane] = (_Float16)a0;
}

__global__ __launch_bounds__(256) void gather_h_k(const float* __restrict__ h_cur,
                                                  const int* __restrict__ row_ptr,
                                                  const int* __restrict__ csr_src,
                                                  _Float16* __restrict__ S_h, int N) {
    const int wave = threadIdx.x >> 6, lane = threadIdx.x & 63;
    const int n = blockIdx.x * 4 + wave;
    if (n >= N) return;
    const int p1 = row_ptr[n + 1];
    float a0 = 0.f, a1 = 0.f;
    for (int p = row_ptr[n]; p < p1; ++p) {
        const int s = csr_src[p];
        a0 += h_cur[(size_t)s * D_NODE + lane];
        a1 += h_cur[(size_t)s * D_NODE + 64 + lane];
    }
    S_h[(size_t)n * D_NODE + lane] = (_Float16)a0;
    S_h[(size_t)n * D_NODE + 64 + lane] = (_Float16)a1;
}

// ---------------- fused node update (MFMA fp16) ----------------
// Block = 256 thr = 4 waves, 16 node-rows per wave (64 rows/block).
// Phase 1: acc1 = h@U1^T (8 col-tiles), acc2 = S_h@U2^T + S_e@U3^T,
//          agg = deg*(acc1+c)+acc2 -> fp16 -> LDS (D-layout -> A-layout transpose).
// Phase 2: per output col-block nb: 6 MFMA chains, GRU nonlinearity (fp32), store fp32.
__global__ __launch_bounds__(256) void node_update(
    const float* __restrict__ h_cur,
    const _Float16* __restrict__ S_h,
    const _Float16* __restrict__ S_e,
    const int* __restrict__ row_ptr,
    const float* __restrict__ cvec,
    const _Float16* __restrict__ UWh,   // [128][336] fp16, this round's slice
    const _Float16* __restrict__ Wihh,  // [384][128] fp16
    const _Float16* __restrict__ Whhh,  // [384][128] fp16
    const float* __restrict__ bih,
    const float* __restrict__ bhh,
    float* __restrict__ h_next,
    int N) {
    __shared__ __align__(16) _Float16 lds_agg[4][16][136];

    const int tid  = threadIdx.x;
    const int wave = tid >> 6;
    const int lane = tid & 63;
    const int l15  = lane & 15;
    const int lg   = lane >> 4;
    const int row_base = blockIdx.x * 64 + wave * 16;
    const int arow = min(row_base + l15, N - 1);   // A-fragment row (clamped; stores guarded)

    const unsigned short* uw  = (const unsigned short*)UWh;
    const unsigned short* wih = (const unsigned short*)Wihh;
    const unsigned short* whh = (const unsigned short*)Whhh;
    const unsigned short* shp = (const unsigned short*)S_h;
    const unsigned short* sep = (const unsigned short*)S_e;

    // h A-frags: row = l&15, k = kb*32 + (l>>4)*8 + j  (fp32 -> fp16 in-register)
    f16x8 a_h[4];
#pragma unroll
    for (int kb = 0; kb < 4; ++kb)
        a_h[kb] = cvt8(h_cur + (size_t)arow * D_NODE + kb * 32 + lg * 8);

    f32x4 acc1[8], acc2[8];
#pragma unroll
    for (int nb = 0; nb < 8; ++nb) {
        acc1[nb] = (f32x4){0.f, 0.f, 0.f, 0.f};
        acc2[nb] = (f32x4){0.f, 0.f, 0.f, 0.f};
    }

    // acc1 = h @ U1^T   (B lane layout mirrors A: col = l&15, k = kb*32+(l>>4)*8+j)
#pragma unroll
    for (int kb = 0; kb < 4; ++kb) {
#pragma unroll
        for (int nb = 0; nb < 8; ++nb) {
            const int col = nb * 16 + l15;
            f16x8 b = as_f16x8(*(const u16x8*)(uw + (size_t)col * D_IN_P + kb * 32 + lg * 8));
            acc1[nb] = __builtin_amdgcn_mfma_f32_16x16x32_f16(a_h[kb], b, acc1[nb], 0, 0, 0);
        }
    }
    // acc2 = S_h @ U2^T
#pragma unroll
    for (int kb = 0; kb < 4; ++kb) {
        f16x8 a = as_f16x8(*(const u16x8*)(shp + (size_t)arow * D_NODE + kb * 32 + lg * 8));
#pragma unroll
        for (int nb = 0; nb < 8; ++nb) {
            const int col = nb * 16 + l15;
            f16x8 b = as_f16x8(*(const u16x8*)(uw + (size_t)col * D_IN_P + 128 + kb * 32 + lg * 8));
            acc2[nb] = __builtin_amdgcn_mfma_f32_16x16x32_f16(a, b, acc2[nb], 0, 0, 0);
        }
    }
    // acc2 += S_e @ U3^T  (K = 64)
#pragma unroll
    for (int kb = 0; kb < 2; ++kb) {
        f16x8 a = as_f16x8(*(const u16x8*)(sep + (size_t)arow * D_EDGE + kb * 32 + lg * 8));
#pragma unroll
        for (int nb = 0; nb < 8; ++nb) {
            const int col = nb * 16 + l15;
            f16x8 b = as_f16x8(*(const u16x8*)(uw + (size_t)col * D_IN_P + 256 + kb * 32 + lg * 8));
            acc2[nb] = __builtin_amdgcn_mfma_f32_16x16x32_f16(a, b, acc2[nb], 0, 0, 0);
        }
    }

    // elementwise: agg = deg*(acc1 + c) + acc2 ; fp16 -> LDS (C/D layout: col=l&15, row=lg*4+i)
    float degv[4];
#pragma unroll
    for (int i = 0; i < 4; ++i) {
        const int n = min(row_base + lg * 4 + i, N - 1);
        degv[i] = (float)(row_ptr[n + 1] - row_ptr[n]);
    }
#pragma unroll
    for (int nb = 0; nb < 8; ++nb) {
        const float cv = cvec[nb * 16 + l15];
#pragma unroll
        for (int i = 0; i < 4; ++i) {
            const float aggv = degv[i] * (acc1[nb][i] + cv) + acc2[nb][i];
            lds_agg[wave][lg * 4 + i][nb * 16 + l15] = (_Float16)aggv;
        }
    }
    __syncthreads();

    // Phase 2: per output col-block
#pragma unroll 1
    for (int nb = 0; nb < 8; ++nb) {
        f32x4 air = {0.f,0.f,0.f,0.f}, aiz = {0.f,0.f,0.f,0.f}, ain = {0.f,0.f,0.f,0.f};
        f32x4 ahr = {0.f,0.f,0.f,0.f}, ahz = {0.f,0.f,0.f,0.f}, ahn = {0.f,0.f,0.f,0.f};
#pragma unroll
        for (int kb = 0; kb < 4; ++kb) {
            f16x8 a_agg = as_f16x8(*(const u16x8*)&lds_agg[wave][l15][kb * 32 + lg * 8]);
            const int c0 = nb * 16 + l15;
            f16x8 b;
            b = as_f16x8(*(const u16x8*)(wih + (size_t)(c0)       * D_NODE + kb * 32 + lg * 8));
            air = __builtin_amdgcn_mfma_f32_16x16x32_f16(a_agg, b, air, 0, 0, 0);
            b = as_f16x8(*(const u16x8*)(wih + (size_t)(c0 + 128) * D_NODE + kb * 32 + lg * 8));
            aiz = __builtin_amdgcn_mfma_f32_16x16x32_f16(a_agg, b, aiz, 0, 0, 0);
            b = as_f16x8(*(const u16x8*)(wih + (size_t)(c0 + 256) * D_NODE + kb * 32 + lg * 8));
            ain = __builtin_amdgcn_mfma_f32_16x16x32_f16(a_agg, b, ain, 0, 0, 0);
            b = as_f16x8(*(const u16x8*)(whh + (size_t)(c0)       * D_NODE + kb * 32 + lg * 8));
            ahr = __builtin_amdgcn_mfma_f32_16x16x32_f16(a_h[kb], b, ahr, 0, 0, 0);
            b = as_f16x8(*(const u16x8*)(whh + (size_t)(c0 + 128) * D_NODE + kb * 32 + lg * 8));
            ahz = __builtin_amdgcn_mfma_f32_16x16x32_f16(a_h[kb], b, ahz, 0, 0, 0);
            b = as_f16x8(*(const u16x8*)(whh + (size_t)(c0 + 256) * D_NODE + kb * 32 + lg * 8));
            ahn = __builtin_amdgcn_mfma_f32_16x16x32_f16(a_h[kb], b, ahn, 0, 0, 0);
        }
        const int d = nb * 16 + l15;
        const float bir = bih[d],       biz = bih[128 + d], bin = bih[256 + d];
        const float bhr = bhh[d],       bhz = bhh[128 + d], bhn = bhh[256 + d];
#pragma unroll
        for (int i = 0; i < 4; ++i) {
            const int n = row_base + lg * 4 + i;
            if (n < N) {
                const float r  = sigm_(air[i] + bir + ahr[i] + bhr);
                const float z  = sigm_(aiz[i] + biz + ahz[i] + bhz);
                const float nn = tanh_(ain[i] + bin + r * (ahn[i] + bhn));
                const float hv = h_cur[(size_t)n * D_NODE + d];
                h_next[(size_t)n * D_NODE + d] = (1.f - z) * nn + z * hv;
            }
        }
    }
}

// ---------------- launch ----------------
extern "C" void kernel_launch(void* const* d_in, const int* in_sizes, int n_in,
                              void* d_out, int out_size, void* d_ws, size_t ws_size,
                              hipStream_t stream) {
    const float* h0   = (const float*)d_in[0];
    const float* e    = (const float*)d_in[1];
    const int*   src  = (const int*)d_in[2];
    const int*   dst  = (const int*)d_in[3];
    const float* cond = (const float*)d_in[4];
    const float* UW   = (const float*)d_in[5];
    const float* Ub   = (const float*)d_in[6];
    const float* Wih  = (const float*)d_in[7];
    const float* Whh  = (const float*)d_in[8];
    const float* bih  = (const float*)d_in[9];
    const float* bhh  = (const float*)d_in[10];

    const int N = in_sizes[0] / D_NODE;
    const int E = in_sizes[2];

    char* wsb = (char*)d_ws;
    size_t off = 0;
    auto carve = [&](size_t bytes) -> char* {
        char* p = wsb + off;
        off = (off + bytes + 255) & ~(size_t)255;
        return p;
    };
    int*   cnt     = (int*)carve((size_t)N * 4);
    int*   row_ptr = (int*)carve(((size_t)N + 1) * 4);
    int*   cursor  = (int*)carve((size_t)N * 4);
    int*   csr_src = (int*)carve((size_t)E * 4);
    int*   csr_eid = (int*)carve((size_t)E * 4);
    float* cvec    = (float*)carve(3 * D_NODE * 4);
    _Float16* S_e  = (_Float16*)carve((size_t)N * D_EDGE * 2);
    _Float16* S_h  = (_Float16*)carve((size_t)N * D_NODE * 2);
    _Float16* UWh  = (_Float16*)carve((size_t)3 * D_NODE * D_IN_P * 2);
    _Float16* Wihh = (_Float16*)carve((size_t)3 * GRU3 * D_NODE * 2);
    _Float16* Whhh = (_Float16*)carve((size_t)3 * GRU3 * D_NODE * 2);
    (void)ws_size; (void)n_in; (void)out_size;

    hipMemsetAsync(cnt, 0, (size_t)N * 4, stream);
    hist_k<<<(E + 255) / 256, 256, 0, stream>>>(dst, cnt, E);
    scan_k<<<1, 1024, 0, stream>>>(cnt, row_ptr, cursor, N);
    scatter_k<<<(E + 255) / 256, 256, 0, stream>>>(src, dst, cursor, csr_src, csr_eid, E);
    compute_c_k<<<1, 384, 0, stream>>>(UW, Ub, cond, cvec);
    cvt_uw_k<<<3 * D_NODE, 384, 0, stream>>>(UW, UWh);
    {
        const int n1 = 3 * GRU3 * D_NODE;
        cvt_f32_k<<<(n1 + 255) / 256, 256, 0, stream>>>(Wih, Wihh, n1);
        cvt_f32_k<<<(n1 + 255) / 256, 256, 0, stream>>>(Whh, Whhh, n1);
    }
    gather_e_k<<<(N + 3) / 4, 256, 0, stream>>>(e, row_ptr, csr_eid, S_e, N);

    float* hout = (float*)d_out;
    const float* hc = h0;
    for (int k = 0; k < 3; ++k) {
        gather_h_k<<<(N + 3) / 4, 256, 0, stream>>>(hc, row_ptr, csr_src, S_h, N);
        node_update<<<(N + 63) / 64, 256, 0, stream>>>(
            hc, S_h, S_e, row_ptr, cvec + k * D_NODE,
            UWh  + (size_t)k * D_NODE * D_IN_P,
            Wihh + (size_t)k * GRU3 * D_NODE,
            Whhh + (size_t)k * GRU3 * D_NODE,
            bih + (size_t)k * GRU3,
            bhh + (size_t)k * GRU3,
            hout, N);   // in-place safe: each block reads/writes only its own rows
        hc = hout;
    }
}

// Round 4
// 888.643 us; speedup vs baseline: 1.2337x; 1.2337x over previous
//
#include <hip/hip_runtime.h>
#include <hip/hip_bf16.h>
#include <hip/hip_fp16.h>

// GGM encode, decomposed (inputs/outputs fp32; internal MFMA in fp16, fp32 accum):
//   agg[v] = deg(v)*(U1 h_v + c_k) + U2*S_h[v] + U3*S_e[v]
//   S_h[v] = sum_{e: dst=v} h[src_e]   (per round, CSR gather, fp32 acc -> fp16)
//   S_e[v] = sum_{e: dst=v} e_e        (once)
//   c_k    = U4 cond + U_b             (once, fp32 exact)
// then GRU: gi = agg@Wih^T + bih, gh = h@Whh^T + bhh, fused elementwise in fp32.
// R3->R4: replaced single-block scan (230us, 1 CU) with 3-kernel hierarchical scan (~8us).

#define D_NODE 128
#define D_EDGE 64
#define D_IN   322
#define D_IN_P 336   // padded fp16 row stride for U_W (16B-aligned fragment loads)
#define GRU3   384

typedef _Float16 f16x8 __attribute__((ext_vector_type(8)));
typedef float    f32x4 __attribute__((ext_vector_type(4)));
typedef unsigned short u16x8 __attribute__((ext_vector_type(8)));

__device__ __forceinline__ f16x8 as_f16x8(u16x8 v) { return __builtin_bit_cast(f16x8, v); }
__device__ __forceinline__ f16x8 cvt8(const float* __restrict__ p) {
    const f32x4 u = *(const f32x4*)p;
    const f32x4 v = *(const f32x4*)(p + 4);
    f16x8 r;
    r[0] = (_Float16)u[0]; r[1] = (_Float16)u[1]; r[2] = (_Float16)u[2]; r[3] = (_Float16)u[3];
    r[4] = (_Float16)v[0]; r[5] = (_Float16)v[1]; r[6] = (_Float16)v[2]; r[7] = (_Float16)v[3];
    return r;
}
__device__ __forceinline__ float sigm_(float x) { return 1.f / (1.f + __expf(-x)); }
__device__ __forceinline__ float tanh_(float x) { return 1.f - 2.f / (__expf(2.f * x) + 1.f); }

// ---------------- CSR build ----------------
__global__ void hist_k(const int* __restrict__ dst, int* __restrict__ cnt, int E) {
    int t = blockIdx.x * 256 + threadIdx.x;
    if (t < E) atomicAdd(&cnt[dst[t]], 1);
}

// Hierarchical exclusive scan of cnt[N] -> row_ptr[N] (+cursor copy), 1024 elems/block.
__global__ __launch_bounds__(256) void scan1_k(const int* __restrict__ cnt, int* __restrict__ row_ptr,
                                               int* __restrict__ blk_sums, int N) {
    __shared__ int s[256];
    const int t = threadIdx.x;
    const int base = blockIdx.x * 1024 + t * 4;
    int v0 = (base + 0 < N) ? cnt[base + 0] : 0;
    int v1 = (base + 1 < N) ? cnt[base + 1] : 0;
    int v2 = (base + 2 < N) ? cnt[base + 2] : 0;
    int v3 = (base + 3 < N) ? cnt[base + 3] : 0;
    const int tot = v0 + v1 + v2 + v3;
    s[t] = tot;
    __syncthreads();
    for (int off = 1; off < 256; off <<= 1) {
        int u = (t >= off) ? s[t - off] : 0;
        __syncthreads();
        s[t] += u;
        __syncthreads();
    }
    const int excl = s[t] - tot;  // exclusive prefix within block
    if (base + 0 < N) row_ptr[base + 0] = excl;
    if (base + 1 < N) row_ptr[base + 1] = excl + v0;
    if (base + 2 < N) row_ptr[base + 2] = excl + v0 + v1;
    if (base + 3 < N) row_ptr[base + 3] = excl + v0 + v1 + v2;
    if (t == 255) blk_sums[blockIdx.x] = s[255];
}

__global__ __launch_bounds__(256) void scan2_k(int* __restrict__ blk_sums, int NB,
                                               int* __restrict__ row_ptr, int N, int E) {
    __shared__ int s[256];
    const int t = threadIdx.x;
    const int v = (t < NB) ? blk_sums[t] : 0;
    s[t] = v;
    __syncthreads();
    for (int off = 1; off < 256; off <<= 1) {
        int u = (t >= off) ? s[t - off] : 0;
        __syncthreads();
        s[t] += u;
        __syncthreads();
    }
    if (t < NB) blk_sums[t] = s[t] - v;  // exclusive block offsets, in place
    if (t == 0) row_ptr[N] = E;          // total = E by construction
}

__global__ __launch_bounds__(256) void scan3_k(int* __restrict__ row_ptr, int* __restrict__ cursor,
                                               const int* __restrict__ blk_sums, int N) {
    const int off = blk_sums[blockIdx.x];
    const int base = blockIdx.x * 1024 + threadIdx.x * 4;
#pragma unroll
    for (int j = 0; j < 4; ++j) {
        const int i = base + j;
        if (i < N) {
            const int v = row_ptr[i] + off;
            row_ptr[i] = v;
            cursor[i] = v;
        }
    }
}

__global__ void scatter_k(const int* __restrict__ src, const int* __restrict__ dst,
                          int* __restrict__ cursor, int* __restrict__ csr_src,
                          int* __restrict__ csr_eid, int E) {
    int t = blockIdx.x * 256 + threadIdx.x;
    if (t < E) {
        int d = dst[t];
        int pos = atomicAdd(&cursor[d], 1);
        csr_src[pos] = src[t];
        csr_eid[pos] = t;
    }
}

// ---------------- weight converts (fp32 -> fp16, once per launch) ----------------
__global__ __launch_bounds__(384) void cvt_uw_k(const float* __restrict__ in, _Float16* __restrict__ out) {
    const int row = blockIdx.x;
    const int t = threadIdx.x;
    if (t < D_IN_P)
        out[row * D_IN_P + t] = (_Float16)(t < D_IN ? in[row * D_IN + t] : 0.f);
}

__global__ void cvt_f32_k(const float* __restrict__ in, _Float16* __restrict__ out, int n) {
    int t = blockIdx.x * 256 + threadIdx.x;
    if (t < n) out[t] = (_Float16)in[t];
}

// ---------------- c_k = U4*cond + U_b (fp32 exact) ----------------
__global__ void compute_c_k(const float* __restrict__ UW, const float* __restrict__ Ub,
                            const float* __restrict__ cond, float* __restrict__ cvec) {
    int t = threadIdx.x;
    if (t < 3 * D_NODE) {
        int k = t >> 7, i = t & 127;
        const float* u = UW + (size_t)k * D_NODE * D_IN + (size_t)i * D_IN + 320;
        cvec[t] = u[0] * cond[0] + u[1] * cond[1] + Ub[k * D_NODE + i];
    }
}

// ---------------- segment sums (CSR gather, wave per node; fp32 acc -> fp16) ----------------
__global__ __launch_bounds__(256) void gather_e_k(const float* __restrict__ e,
                                                  const int* __restrict__ row_ptr,
                                                  const int* __restrict__ csr_eid,
                                                  _Float16* __restrict__ S_e, int N) {
    const int wave = threadIdx.x >> 6, lane = threadIdx.x & 63;
    const int n = blockIdx.x * 4 + wave;
    if (n >= N) return;
    const int p1 = row_ptr[n + 1];
    float a0 = 0.f;
    for (int p = row_ptr[n]; p < p1; ++p) {
        const int eid = csr_eid[p];
        a0 += e[(size_t)eid * D_EDGE + lane];
    }
    S_e[(size_t)n * D_EDGE + lane] = (_Float16)a0;
}

__global__ __launch_bounds__(256) void gather_h_k(const float* __restrict__ h_cur,
                                                  const int* __restrict__ row_ptr,
                                                  const int* __restrict__ csr_src,
                                                  _Float16* __restrict__ S_h, int N) {
    const int wave = threadIdx.x >> 6, lane = threadIdx.x & 63;
    const int n = blockIdx.x * 4 + wave;
    if (n >= N) return;
    const int p1 = row_ptr[n + 1];
    float a0 = 0.f, a1 = 0.f;
    for (int p = row_ptr[n]; p < p1; ++p) {
        const int s = csr_src[p];
        a0 += h_cur[(size_t)s * D_NODE + lane];
        a1 += h_cur[(size_t)s * D_NODE + 64 + lane];
    }
    S_h[(size_t)n * D_NODE + lane] = (_Float16)a0;
    S_h[(size_t)n * D_NODE + 64 + lane] = (_Float16)a1;
}

// ---------------- fused node update (MFMA fp16) ----------------
__global__ __launch_bounds__(256) void node_update(
    const float* __restrict__ h_cur,
    const _Float16* __restrict__ S_h,
    const _Float16* __restrict__ S_e,
    const int* __restrict__ row_ptr,
    const float* __restrict__ cvec,
    const _Float16* __restrict__ UWh,   // [128][336] fp16, this round's slice
    const _Float16* __restrict__ Wihh,  // [384][128] fp16
    const _Float16* __restrict__ Whhh,  // [384][128] fp16
    const float* __restrict__ bih,
    const float* __restrict__ bhh,
    float* __restrict__ h_next,
    int N) {
    __shared__ __align__(16) _Float16 lds_agg[4][16][136];

    const int tid  = threadIdx.x;
    const int wave = tid >> 6;
    const int lane = tid & 63;
    const int l15  = lane & 15;
    const int lg   = lane >> 4;
    const int row_base = blockIdx.x * 64 + wave * 16;
    const int arow = min(row_base + l15, N - 1);   // A-fragment row (clamped; stores guarded)

    const unsigned short* uw  = (const unsigned short*)UWh;
    const unsigned short* wih = (const unsigned short*)Wihh;
    const unsigned short* whh = (const unsigned short*)Whhh;
    const unsigned short* shp = (const unsigned short*)S_h;
    const unsigned short* sep = (const unsigned short*)S_e;

    // h A-frags: row = l&15, k = kb*32 + (l>>4)*8 + j  (fp32 -> fp16 in-register)
    f16x8 a_h[4];
#pragma unroll
    for (int kb = 0; kb < 4; ++kb)
        a_h[kb] = cvt8(h_cur + (size_t)arow * D_NODE + kb * 32 + lg * 8);

    f32x4 acc1[8], acc2[8];
#pragma unroll
    for (int nb = 0; nb < 8; ++nb) {
        acc1[nb] = (f32x4){0.f, 0.f, 0.f, 0.f};
        acc2[nb] = (f32x4){0.f, 0.f, 0.f, 0.f};
    }

    // acc1 = h @ U1^T   (B lane layout mirrors A: col = l&15, k = kb*32+(l>>4)*8+j)
#pragma unroll
    for (int kb = 0; kb < 4; ++kb) {
#pragma unroll
        for (int nb = 0; nb < 8; ++nb) {
            const int col = nb * 16 + l15;
            f16x8 b = as_f16x8(*(const u16x8*)(uw + (size_t)col * D_IN_P + kb * 32 + lg * 8));
            acc1[nb] = __builtin_amdgcn_mfma_f32_16x16x32_f16(a_h[kb], b, acc1[nb], 0, 0, 0);
        }
    }
    // acc2 = S_h @ U2^T
#pragma unroll
    for (int kb = 0; kb < 4; ++kb) {
        f16x8 a = as_f16x8(*(const u16x8*)(shp + (size_t)arow * D_NODE + kb * 32 + lg * 8));
#pragma unroll
        for (int nb = 0; nb < 8; ++nb) {
            const int col = nb * 16 + l15;
            f16x8 b = as_f16x8(*(const u16x8*)(uw + (size_t)col * D_IN_P + 128 + kb * 32 + lg * 8));
            acc2[nb] = __builtin_amdgcn_mfma_f32_16x16x32_f16(a, b, acc2[nb], 0, 0, 0);
        }
    }
    // acc2 += S_e @ U3^T  (K = 64)
#pragma unroll
    for (int kb = 0; kb < 2; ++kb) {
        f16x8 a = as_f16x8(*(const u16x8*)(sep + (size_t)arow * D_EDGE + kb * 32 + lg * 8));
#pragma unroll
        for (int nb = 0; nb < 8; ++nb) {
            const int col = nb * 16 + l15;
            f16x8 b = as_f16x8(*(const u16x8*)(uw + (size_t)col * D_IN_P + 256 + kb * 32 + lg * 8));
            acc2[nb] = __builtin_amdgcn_mfma_f32_16x16x32_f16(a, b, acc2[nb], 0, 0, 0);
        }
    }

    // elementwise: agg = deg*(acc1 + c) + acc2 ; fp16 -> LDS (C/D layout: col=l&15, row=lg*4+i)
    float degv[4];
#pragma unroll
    for (int i = 0; i < 4; ++i) {
        const int n = min(row_base + lg * 4 + i, N - 1);
        degv[i] = (float)(row_ptr[n + 1] - row_ptr[n]);
    }
#pragma unroll
    for (int nb = 0; nb < 8; ++nb) {
        const float cv = cvec[nb * 16 + l15];
#pragma unroll
        for (int i = 0; i < 4; ++i) {
            const float aggv = degv[i] * (acc1[nb][i] + cv) + acc2[nb][i];
            lds_agg[wave][lg * 4 + i][nb * 16 + l15] = (_Float16)aggv;
        }
    }
    __syncthreads();

    // Phase 2: per output col-block
#pragma unroll 1
    for (int nb = 0; nb < 8; ++nb) {
        f32x4 air = {0.f,0.f,0.f,0.f}, aiz = {0.f,0.f,0.f,0.f}, ain = {0.f,0.f,0.f,0.f};
        f32x4 ahr = {0.f,0.f,0.f,0.f}, ahz = {0.f,0.f,0.f,0.f}, ahn = {0.f,0.f,0.f,0.f};
#pragma unroll
        for (int kb = 0; kb < 4; ++kb) {
            f16x8 a_agg = as_f16x8(*(const u16x8*)&lds_agg[wave][l15][kb * 32 + lg * 8]);
            const int c0 = nb * 16 + l15;
            f16x8 b;
            b = as_f16x8(*(const u16x8*)(wih + (size_t)(c0)       * D_NODE + kb * 32 + lg * 8));
            air = __builtin_amdgcn_mfma_f32_16x16x32_f16(a_agg, b, air, 0, 0, 0);
            b = as_f16x8(*(const u16x8*)(wih + (size_t)(c0 + 128) * D_NODE + kb * 32 + lg * 8));
            aiz = __builtin_amdgcn_mfma_f32_16x16x32_f16(a_agg, b, aiz, 0, 0, 0);
            b = as_f16x8(*(const u16x8*)(wih + (size_t)(c0 + 256) * D_NODE + kb * 32 + lg * 8));
            ain = __builtin_amdgcn_mfma_f32_16x16x32_f16(a_agg, b, ain, 0, 0, 0);
            b = as_f16x8(*(const u16x8*)(whh + (size_t)(c0)       * D_NODE + kb * 32 + lg * 8));
            ahr = __builtin_amdgcn_mfma_f32_16x16x32_f16(a_h[kb], b, ahr, 0, 0, 0);
            b = as_f16x8(*(const u16x8*)(whh + (size_t)(c0 + 128) * D_NODE + kb * 32 + lg * 8));
            ahz = __builtin_amdgcn_mfma_f32_16x16x32_f16(a_h[kb], b, ahz, 0, 0, 0);
            b = as_f16x8(*(const u16x8*)(whh + (size_t)(c0 + 256) * D_NODE + kb * 32 + lg * 8));
            ahn = __builtin_amdgcn_mfma_f32_16x16x32_f16(a_h[kb], b, ahn, 0, 0, 0);
        }
        const int d = nb * 16 + l15;
        const float bir = bih[d],       biz = bih[128 + d], bin = bih[256 + d];
        const float bhr = bhh[d],       bhz = bhh[128 + d], bhn = bhh[256 + d];
#pragma unroll
        for (int i = 0; i < 4; ++i) {
            const int n = row_base + lg * 4 + i;
            if (n < N) {
                const float r  = sigm_(air[i] + bir + ahr[i] + bhr);
                const float z  = sigm_(aiz[i] + biz + ahz[i] + bhz);
                const float nn = tanh_(ain[i] + bin + r * (ahn[i] + bhn));
                const float hv = h_cur[(size_t)n * D_NODE + d];
                h_next[(size_t)n * D_NODE + d] = (1.f - z) * nn + z * hv;
            }
        }
    }
}

// ---------------- launch ----------------
extern "C" void kernel_launch(void* const* d_in, const int* in_sizes, int n_in,
                              void* d_out, int out_size, void* d_ws, size_t ws_size,
                              hipStream_t stream) {
    const float* h0   = (const float*)d_in[0];
    const float* e    = (const float*)d_in[1];
    const int*   src  = (const int*)d_in[2];
    const int*   dst  = (const int*)d_in[3];
    const float* cond = (const float*)d_in[4];
    const float* UW   = (const float*)d_in[5];
    const float* Ub   = (const float*)d_in[6];
    const float* Wih  = (const float*)d_in[7];
    const float* Whh  = (const float*)d_in[8];
    const float* bih  = (const float*)d_in[9];
    const float* bhh  = (const float*)d_in[10];

    const int N = in_sizes[0] / D_NODE;
    const int E = in_sizes[2];
    const int NB = (N + 1023) / 1024;   // scan blocks (must be <= 256)

    char* wsb = (char*)d_ws;
    size_t off = 0;
    auto carve = [&](size_t bytes) -> char* {
        char* p = wsb + off;
        off = (off + bytes + 255) & ~(size_t)255;
        return p;
    };
    int*   cnt      = (int*)carve((size_t)N * 4);
    int*   row_ptr  = (int*)carve(((size_t)N + 1) * 4);
    int*   cursor   = (int*)carve((size_t)N * 4);
    int*   csr_src  = (int*)carve((size_t)E * 4);
    int*   csr_eid  = (int*)carve((size_t)E * 4);
    int*   blk_sums = (int*)carve(256 * 4);
    float* cvec     = (float*)carve(3 * D_NODE * 4);
    _Float16* S_e  = (_Float16*)carve((size_t)N * D_EDGE * 2);
    _Float16* S_h  = (_Float16*)carve((size_t)N * D_NODE * 2);
    _Float16* UWh  = (_Float16*)carve((size_t)3 * D_NODE * D_IN_P * 2);
    _Float16* Wihh = (_Float16*)carve((size_t)3 * GRU3 * D_NODE * 2);
    _Float16* Whhh = (_Float16*)carve((size_t)3 * GRU3 * D_NODE * 2);
    (void)ws_size; (void)n_in; (void)out_size;

    hipMemsetAsync(cnt, 0, (size_t)N * 4, stream);
    hist_k<<<(E + 255) / 256, 256, 0, stream>>>(dst, cnt, E);
    scan1_k<<<NB, 256, 0, stream>>>(cnt, row_ptr, blk_sums, N);
    scan2_k<<<1, 256, 0, stream>>>(blk_sums, NB, row_ptr, N, E);
    scan3_k<<<NB, 256, 0, stream>>>(row_ptr, cursor, blk_sums, N);
    scatter_k<<<(E + 255) / 256, 256, 0, stream>>>(src, dst, cursor, csr_src, csr_eid, E);
    compute_c_k<<<1, 384, 0, stream>>>(UW, Ub, cond, cvec);
    cvt_uw_k<<<3 * D_NODE, 384, 0, stream>>>(UW, UWh);
    {
        const int n1 = 3 * GRU3 * D_NODE;
        cvt_f32_k<<<(n1 + 255) / 256, 256, 0, stream>>>(Wih, Wihh, n1);
        cvt_f32_k<<<(n1 + 255) / 256, 256, 0, stream>>>(Whh, Whhh, n1);
    }
    gather_e_k<<<(N + 3) / 4, 256, 0, stream>>>(e, row_ptr, csr_eid, S_e, N);

    float* hout = (float*)d_out;
    const float* hc = h0;
    for (int k = 0; k < 3; ++k) {
        gather_h_k<<<(N + 3) / 4, 256, 0, stream>>>(hc, row_ptr, csr_src, S_h, N);
        node_update<<<(N + 63) / 64, 256, 0, stream>>>(
            hc, S_h, S_e, row_ptr, cvec + k * D_NODE,
            UWh  + (size_t)k * D_NODE * D_IN_P,
            Wihh + (size_t)k * GRU3 * D_NODE,
            Whhh + (size_t)k * GRU3 * D_NODE,
            bih + (size_t)k * GRU3,
            bhh + (size_t)k * GRU3,
            hout, N);   // in-place safe: each block reads/writes only its own rows
        hc = hout;
    }
}

// Round 5
// 879.840 us; speedup vs baseline: 1.2461x; 1.0100x over previous
//
#include <hip/hip_runtime.h>
#include <hip/hip_bf16.h>
#include <hip/hip_fp16.h>

// GGM encode, decomposed (inputs/outputs fp32; internal MFMA in fp16, fp32 accum):
//   agg[v] = deg(v)*(U1 h_v + c_k) + U2*S_h[v] + U3*S_e[v]
//   S_h[v] = sum_{e: dst=v} h[src_e]   (per round, CSR gather, fp32 acc -> fp16)
//   S_e[v] = sum_{e: dst=v} e_e        (once)
//   c_k    = U4 cond + U_b             (once, fp32 exact)
// then GRU: gi = agg@Wih^T + bih, gh = h@Whh^T + bhh, fused elementwise in fp32.
// R4->R5: node_update restructured for weight reuse: 128 rows/block, 2 m-tiles/wave,
// nb-outer loops, S_h/S_e/agg staged in LDS. Halves L2 weight traffic (1.74->0.87 GB),
// 2 MFMA per B-load instead of 1.

#define D_NODE 128
#define D_EDGE 64
#define D_IN   322
#define D_IN_P 336   // padded fp16 row stride for U_W (16B-aligned fragment loads)
#define GRU3   384
#define ROWS_BLK 128

typedef _Float16 f16x8 __attribute__((ext_vector_type(8)));
typedef float    f32x4 __attribute__((ext_vector_type(4)));
typedef unsigned short u16x8 __attribute__((ext_vector_type(8)));

__device__ __forceinline__ f16x8 as_f16x8(u16x8 v) { return __builtin_bit_cast(f16x8, v); }
__device__ __forceinline__ f16x8 cvt8(const float* __restrict__ p) {
    const f32x4 u = *(const f32x4*)p;
    const f32x4 v = *(const f32x4*)(p + 4);
    f16x8 r;
    r[0] = (_Float16)u[0]; r[1] = (_Float16)u[1]; r[2] = (_Float16)u[2]; r[3] = (_Float16)u[3];
    r[4] = (_Float16)v[0]; r[5] = (_Float16)v[1]; r[6] = (_Float16)v[2]; r[7] = (_Float16)v[3];
    return r;
}
__device__ __forceinline__ float sigm_(float x) { return 1.f / (1.f + __expf(-x)); }
__device__ __forceinline__ float tanh_(float x) { return 1.f - 2.f / (__expf(2.f * x) + 1.f); }

// ---------------- CSR build ----------------
__global__ void hist_k(const int* __restrict__ dst, int* __restrict__ cnt, int E) {
    int t = blockIdx.x * 256 + threadIdx.x;
    if (t < E) atomicAdd(&cnt[dst[t]], 1);
}

__global__ __launch_bounds__(256) void scan1_k(const int* __restrict__ cnt, int* __restrict__ row_ptr,
                                               int* __restrict__ blk_sums, int N) {
    __shared__ int s[256];
    const int t = threadIdx.x;
    const int base = blockIdx.x * 1024 + t * 4;
    int v0 = (base + 0 < N) ? cnt[base + 0] : 0;
    int v1 = (base + 1 < N) ? cnt[base + 1] : 0;
    int v2 = (base + 2 < N) ? cnt[base + 2] : 0;
    int v3 = (base + 3 < N) ? cnt[base + 3] : 0;
    const int tot = v0 + v1 + v2 + v3;
    s[t] = tot;
    __syncthreads();
    for (int off = 1; off < 256; off <<= 1) {
        int u = (t >= off) ? s[t - off] : 0;
        __syncthreads();
        s[t] += u;
        __syncthreads();
    }
    const int excl = s[t] - tot;
    if (base + 0 < N) row_ptr[base + 0] = excl;
    if (base + 1 < N) row_ptr[base + 1] = excl + v0;
    if (base + 2 < N) row_ptr[base + 2] = excl + v0 + v1;
    if (base + 3 < N) row_ptr[base + 3] = excl + v0 + v1 + v2;
    if (t == 255) blk_sums[blockIdx.x] = s[255];
}

__global__ __launch_bounds__(256) void scan2_k(int* __restrict__ blk_sums, int NB,
                                               int* __restrict__ row_ptr, int N, int E) {
    __shared__ int s[256];
    const int t = threadIdx.x;
    const int v = (t < NB) ? blk_sums[t] : 0;
    s[t] = v;
    __syncthreads();
    for (int off = 1; off < 256; off <<= 1) {
        int u = (t >= off) ? s[t - off] : 0;
        __syncthreads();
        s[t] += u;
        __syncthreads();
    }
    if (t < NB) blk_sums[t] = s[t] - v;
    if (t == 0) row_ptr[N] = E;
}

__global__ __launch_bounds__(256) void scan3_k(int* __restrict__ row_ptr, int* __restrict__ cursor,
                                               const int* __restrict__ blk_sums, int N) {
    const int off = blk_sums[blockIdx.x];
    const int base = blockIdx.x * 1024 + threadIdx.x * 4;
#pragma unroll
    for (int j = 0; j < 4; ++j) {
        const int i = base + j;
        if (i < N) {
            const int v = row_ptr[i] + off;
            row_ptr[i] = v;
            cursor[i] = v;
        }
    }
}

__global__ void scatter_k(const int* __restrict__ src, const int* __restrict__ dst,
                          int* __restrict__ cursor, int* __restrict__ csr_src,
                          int* __restrict__ csr_eid, int E) {
    int t = blockIdx.x * 256 + threadIdx.x;
    if (t < E) {
        int d = dst[t];
        int pos = atomicAdd(&cursor[d], 1);
        csr_src[pos] = src[t];
        csr_eid[pos] = t;
    }
}

// ---------------- weight converts (fp32 -> fp16, once per launch) ----------------
__global__ __launch_bounds__(384) void cvt_uw_k(const float* __restrict__ in, _Float16* __restrict__ out) {
    const int row = blockIdx.x;
    const int t = threadIdx.x;
    if (t < D_IN_P)
        out[row * D_IN_P + t] = (_Float16)(t < D_IN ? in[row * D_IN + t] : 0.f);
}

__global__ void cvt_f32_k(const float* __restrict__ in, _Float16* __restrict__ out, int n) {
    int t = blockIdx.x * 256 + threadIdx.x;
    if (t < n) out[t] = (_Float16)in[t];
}

// ---------------- c_k = U4*cond + U_b (fp32 exact) ----------------
__global__ void compute_c_k(const float* __restrict__ UW, const float* __restrict__ Ub,
                            const float* __restrict__ cond, float* __restrict__ cvec) {
    int t = threadIdx.x;
    if (t < 3 * D_NODE) {
        int k = t >> 7, i = t & 127;
        const float* u = UW + (size_t)k * D_NODE * D_IN + (size_t)i * D_IN + 320;
        cvec[t] = u[0] * cond[0] + u[1] * cond[1] + Ub[k * D_NODE + i];
    }
}

// ---------------- segment sums (CSR gather, wave per node; fp32 acc -> fp16) ----------------
__global__ __launch_bounds__(256) void gather_e_k(const float* __restrict__ e,
                                                  const int* __restrict__ row_ptr,
                                                  const int* __restrict__ csr_eid,
                                                  _Float16* __restrict__ S_e, int N) {
    const int wave = threadIdx.x >> 6, lane = threadIdx.x & 63;
    const int n = blockIdx.x * 4 + wave;
    if (n >= N) return;
    const int p1 = row_ptr[n + 1];
    float a0 = 0.f;
    for (int p = row_ptr[n]; p < p1; ++p) {
        const int eid = csr_eid[p];
        a0 += e[(size_t)eid * D_EDGE + lane];
    }
    S_e[(size_t)n * D_EDGE + lane] = (_Float16)a0;
}

__global__ __launch_bounds__(256) void gather_h_k(const float* __restrict__ h_cur,
                                                  const int* __restrict__ row_ptr,
                                                  const int* __restrict__ csr_src,
                                                  _Float16* __restrict__ S_h, int N) {
    const int wave = threadIdx.x >> 6, lane = threadIdx.x & 63;
    const int n = blockIdx.x * 4 + wave;
    if (n >= N) return;
    const int p1 = row_ptr[n + 1];
    float a0 = 0.f, a1 = 0.f;
    for (int p = row_ptr[n]; p < p1; ++p) {
        const int s = csr_src[p];
        a0 += h_cur[(size_t)s * D_NODE + lane];
        a1 += h_cur[(size_t)s * D_NODE + 64 + lane];
    }
    S_h[(size_t)n * D_NODE + lane] = (_Float16)a0;
    S_h[(size_t)n * D_NODE + 64 + lane] = (_Float16)a1;
}

// ---------------- fused node update (MFMA fp16), v2 ----------------
// Block = 256 thr (4 waves), 128 rows/block; wave w owns rows w*32..w*32+31 (2 m-tiles).
// S_h/S_e staged to LDS cooperatively; agg through LDS (C-layout -> A-layout transpose).
// nb-outer: per nb, each B fragment is loaded once and feeds 2 MFMAs (m=0,1).
__global__ __launch_bounds__(256) void node_update(
    const float* __restrict__ h_cur,
    const _Float16* __restrict__ S_h,
    const _Float16* __restrict__ S_e,
    const int* __restrict__ row_ptr,
    const float* __restrict__ cvec,
    const _Float16* __restrict__ UWh,   // [128][336] fp16, this round's slice
    const _Float16* __restrict__ Wihh,  // [384][128] fp16
    const _Float16* __restrict__ Whhh,  // [384][128] fp16
    const float* __restrict__ bih,
    const float* __restrict__ bhh,
    float* __restrict__ h_next,
    int N) {
    __shared__ __align__(16) _Float16 lds_sh[ROWS_BLK][136];
    __shared__ __align__(16) _Float16 lds_se[ROWS_BLK][72];
    __shared__ __align__(16) _Float16 lds_agg[ROWS_BLK][136];

    const int tid  = threadIdx.x;
    const int row0 = blockIdx.x * ROWS_BLK;

    const unsigned short* uw  = (const unsigned short*)UWh;
    const unsigned short* wih = (const unsigned short*)Wihh;
    const unsigned short* whh = (const unsigned short*)Whhh;
    const unsigned short* shp = (const unsigned short*)S_h;
    const unsigned short* sep = (const unsigned short*)S_e;

    // ---- cooperative staging: S_h (8 passes), S_e (4 passes); loads first, then writes ----
    {
        u16x8 th[8];
        const int r = tid >> 4, c8 = (tid & 15) * 8;
#pragma unroll
        for (int p = 0; p < 8; ++p) {
            const int g = min(row0 + p * 16 + r, N - 1);
            th[p] = *(const u16x8*)(shp + (size_t)g * D_NODE + c8);
        }
        u16x8 te[4];
        const int re = tid >> 3, ce8 = (tid & 7) * 8;
#pragma unroll
        for (int p = 0; p < 4; ++p) {
            const int g = min(row0 + p * 32 + re, N - 1);
            te[p] = *(const u16x8*)(sep + (size_t)g * D_EDGE + ce8);
        }
#pragma unroll
        for (int p = 0; p < 8; ++p) *(u16x8*)&lds_sh[p * 16 + r][c8] = th[p];
#pragma unroll
        for (int p = 0; p < 4; ++p) *(u16x8*)&lds_se[p * 32 + re][ce8] = te[p];
    }
    __syncthreads();

    const int wave = tid >> 6;
    const int lane = tid & 63;
    const int l15  = lane & 15;
    const int lg   = lane >> 4;
    const int wrow = wave * 32;          // wave's first row within block
    const int rbase = row0 + wrow;       // global

    // h A-frags for both m-tiles (fp32 -> fp16 in-register); reused in phase 1 and 2.
    f16x8 a_h[2][4];
#pragma unroll
    for (int m = 0; m < 2; ++m) {
        const int arow = min(rbase + m * 16 + l15, N - 1);
#pragma unroll
        for (int kb = 0; kb < 4; ++kb)
            a_h[m][kb] = cvt8(h_cur + (size_t)arow * D_NODE + kb * 32 + lg * 8);
    }

    // deg in C-layout (rows lg*4+i within each m-tile)
    float degv[2][4];
#pragma unroll
    for (int m = 0; m < 2; ++m)
#pragma unroll
        for (int i = 0; i < 4; ++i) {
            const int n = min(rbase + m * 16 + lg * 4 + i, N - 1);
            degv[m][i] = (float)(row_ptr[n + 1] - row_ptr[n]);
        }

    // ---- Phase 1: agg = deg*(U1 h + c) + U2 S_h + U3 S_e, per output col-block nb ----
#pragma unroll 1
    for (int nb = 0; nb < 8; ++nb) {
        const int col = nb * 16 + l15;
        f32x4 acc1[2] = {{0.f,0.f,0.f,0.f},{0.f,0.f,0.f,0.f}};
        f32x4 acc2[2] = {{0.f,0.f,0.f,0.f},{0.f,0.f,0.f,0.f}};
#pragma unroll
        for (int kb = 0; kb < 4; ++kb) {   // U1: A = h (regs)
            f16x8 b = as_f16x8(*(const u16x8*)(uw + (size_t)col * D_IN_P + kb * 32 + lg * 8));
            acc1[0] = __builtin_amdgcn_mfma_f32_16x16x32_f16(a_h[0][kb], b, acc1[0], 0, 0, 0);
            acc1[1] = __builtin_amdgcn_mfma_f32_16x16x32_f16(a_h[1][kb], b, acc1[1], 0, 0, 0);
        }
#pragma unroll
        for (int kb = 0; kb < 4; ++kb) {   // U2: A = S_h (LDS)
            f16x8 b = as_f16x8(*(const u16x8*)(uw + (size_t)col * D_IN_P + 128 + kb * 32 + lg * 8));
            f16x8 a0 = as_f16x8(*(const u16x8*)&lds_sh[wrow + l15][kb * 32 + lg * 8]);
            f16x8 a1 = as_f16x8(*(const u16x8*)&lds_sh[wrow + 16 + l15][kb * 32 + lg * 8]);
            acc2[0] = __builtin_amdgcn_mfma_f32_16x16x32_f16(a0, b, acc2[0], 0, 0, 0);
            acc2[1] = __builtin_amdgcn_mfma_f32_16x16x32_f16(a1, b, acc2[1], 0, 0, 0);
        }
#pragma unroll
        for (int kb = 0; kb < 2; ++kb) {   // U3: A = S_e (LDS)
            f16x8 b = as_f16x8(*(const u16x8*)(uw + (size_t)col * D_IN_P + 256 + kb * 32 + lg * 8));
            f16x8 a0 = as_f16x8(*(const u16x8*)&lds_se[wrow + l15][kb * 32 + lg * 8]);
            f16x8 a1 = as_f16x8(*(const u16x8*)&lds_se[wrow + 16 + l15][kb * 32 + lg * 8]);
            acc2[0] = __builtin_amdgcn_mfma_f32_16x16x32_f16(a0, b, acc2[0], 0, 0, 0);
            acc2[1] = __builtin_amdgcn_mfma_f32_16x16x32_f16(a1, b, acc2[1], 0, 0, 0);
        }
        const float cv = cvec[col];
#pragma unroll
        for (int m = 0; m < 2; ++m)
#pragma unroll
            for (int i = 0; i < 4; ++i) {
                const float aggv = degv[m][i] * (acc1[m][i] + cv) + acc2[m][i];
                lds_agg[wrow + m * 16 + lg * 4 + i][nb * 16 + l15] = (_Float16)aggv;
            }
    }
    __syncthreads();   // agg C-layout -> A-layout visibility (cross-lane)

    // ---- Phase 2: GRU gates, per output col-block nb ----
#pragma unroll 1
    for (int nb = 0; nb < 8; ++nb) {
        const int c0 = nb * 16 + l15;
        f32x4 air[2] = {{0.f,0.f,0.f,0.f},{0.f,0.f,0.f,0.f}};
        f32x4 aiz[2] = {{0.f,0.f,0.f,0.f},{0.f,0.f,0.f,0.f}};
        f32x4 ain_[2] = {{0.f,0.f,0.f,0.f},{0.f,0.f,0.f,0.f}};
        f32x4 ahr[2] = {{0.f,0.f,0.f,0.f},{0.f,0.f,0.f,0.f}};
        f32x4 ahz[2] = {{0.f,0.f,0.f,0.f},{0.f,0.f,0.f,0.f}};
        f32x4 ahn[2] = {{0.f,0.f,0.f,0.f},{0.f,0.f,0.f,0.f}};
#pragma unroll
        for (int kb = 0; kb < 4; ++kb) {
            f16x8 ag0 = as_f16x8(*(const u16x8*)&lds_agg[wrow + l15][kb * 32 + lg * 8]);
            f16x8 ag1 = as_f16x8(*(const u16x8*)&lds_agg[wrow + 16 + l15][kb * 32 + lg * 8]);
            f16x8 b;
            b = as_f16x8(*(const u16x8*)(wih + (size_t)(c0)       * D_NODE + kb * 32 + lg * 8));
            air[0] = __builtin_amdgcn_mfma_f32_16x16x32_f16(ag0, b, air[0], 0, 0, 0);
            air[1] = __builtin_amdgcn_mfma_f32_16x16x32_f16(ag1, b, air[1], 0, 0, 0);
            b = as_f16x8(*(const u16x8*)(wih + (size_t)(c0 + 128) * D_NODE + kb * 32 + lg * 8));
            aiz[0] = __builtin_amdgcn_mfma_f32_16x16x32_f16(ag0, b, aiz[0], 0, 0, 0);
            aiz[1] = __builtin_amdgcn_mfma_f32_16x16x32_f16(ag1, b, aiz[1], 0, 0, 0);
            b = as_f16x8(*(const u16x8*)(wih + (size_t)(c0 + 256) * D_NODE + kb * 32 + lg * 8));
            ain_[0] = __builtin_amdgcn_mfma_f32_16x16x32_f16(ag0, b, ain_[0], 0, 0, 0);
            ain_[1] = __builtin_amdgcn_mfma_f32_16x16x32_f16(ag1, b, ain_[1], 0, 0, 0);
            b = as_f16x8(*(const u16x8*)(whh + (size_t)(c0)       * D_NODE + kb * 32 + lg * 8));
            ahr[0] = __builtin_amdgcn_mfma_f32_16x16x32_f16(a_h[0][kb], b, ahr[0], 0, 0, 0);
            ahr[1] = __builtin_amdgcn_mfma_f32_16x16x32_f16(a_h[1][kb], b, ahr[1], 0, 0, 0);
            b = as_f16x8(*(const u16x8*)(whh + (size_t)(c0 + 128) * D_NODE + kb * 32 + lg * 8));
            ahz[0] = __builtin_amdgcn_mfma_f32_16x16x32_f16(a_h[0][kb], b, ahz[0], 0, 0, 0);
            ahz[1] = __builtin_amdgcn_mfma_f32_16x16x32_f16(a_h[1][kb], b, ahz[1], 0, 0, 0);
            b = as_f16x8(*(const u16x8*)(whh + (size_t)(c0 + 256) * D_NODE + kb * 32 + lg * 8));
            ahn[0] = __builtin_amdgcn_mfma_f32_16x16x32_f16(a_h[0][kb], b, ahn[0], 0, 0, 0);
            ahn[1] = __builtin_amdgcn_mfma_f32_16x16x32_f16(a_h[1][kb], b, ahn[1], 0, 0, 0);
        }
        const int d = c0;
        const float bir = bih[d],  biz = bih[128 + d], bin = bih[256 + d];
        const float bhr = bhh[d],  bhz = bhh[128 + d], bhn = bhh[256 + d];
#pragma unroll
        for (int m = 0; m < 2; ++m)
#pragma unroll
            for (int i = 0; i < 4; ++i) {
                const int n = rbase + m * 16 + lg * 4 + i;
                if (n < N) {
                    const float r  = sigm_(air[m][i] + bir + ahr[m][i] + bhr);
                    const float z  = sigm_(aiz[m][i] + biz + ahz[m][i] + bhz);
                    const float nn = tanh_(ain_[m][i] + bin + r * (ahn[m][i] + bhn));
                    const float hv = h_cur[(size_t)n * D_NODE + d];
                    h_next[(size_t)n * D_NODE + d] = (1.f - z) * nn + z * hv;
                }
            }
    }
}

// ---------------- launch ----------------
extern "C" void kernel_launch(void* const* d_in, const int* in_sizes, int n_in,
                              void* d_out, int out_size, void* d_ws, size_t ws_size,
                              hipStream_t stream) {
    const float* h0   = (const float*)d_in[0];
    const float* e    = (const float*)d_in[1];
    const int*   src  = (const int*)d_in[2];
    const int*   dst  = (const int*)d_in[3];
    const float* cond = (const float*)d_in[4];
    const float* UW   = (const float*)d_in[5];
    const float* Ub   = (const float*)d_in[6];
    const float* Wih  = (const float*)d_in[7];
    const float* Whh  = (const float*)d_in[8];
    const float* bih  = (const float*)d_in[9];
    const float* bhh  = (const float*)d_in[10];

    const int N = in_sizes[0] / D_NODE;
    const int E = in_sizes[2];
    const int NB = (N + 1023) / 1024;   // scan blocks (<= 256)

    char* wsb = (char*)d_ws;
    size_t off = 0;
    auto carve = [&](size_t bytes) -> char* {
        char* p = wsb + off;
        off = (off + bytes + 255) & ~(size_t)255;
        return p;
    };
    int*   cnt      = (int*)carve((size_t)N * 4);
    int*   row_ptr  = (int*)carve(((size_t)N + 1) * 4);
    int*   cursor   = (int*)carve((size_t)N * 4);
    int*   csr_src  = (int*)carve((size_t)E * 4);
    int*   csr_eid  = (int*)carve((size_t)E * 4);
    int*   blk_sums = (int*)carve(256 * 4);
    float* cvec     = (float*)carve(3 * D_NODE * 4);
    _Float16* S_e  = (_Float16*)carve((size_t)N * D_EDGE * 2);
    _Float16* S_h  = (_Float16*)carve((size_t)N * D_NODE * 2);
    _Float16* UWh  = (_Float16*)carve((size_t)3 * D_NODE * D_IN_P * 2);
    _Float16* Wihh = (_Float16*)carve((size_t)3 * GRU3 * D_NODE * 2);
    _Float16* Whhh = (_Float16*)carve((size_t)3 * GRU3 * D_NODE * 2);
    (void)ws_size; (void)n_in; (void)out_size;

    hipMemsetAsync(cnt, 0, (size_t)N * 4, stream);
    hist_k<<<(E + 255) / 256, 256, 0, stream>>>(dst, cnt, E);
    scan1_k<<<NB, 256, 0, stream>>>(cnt, row_ptr, blk_sums, N);
    scan2_k<<<1, 256, 0, stream>>>(blk_sums, NB, row_ptr, N, E);
    scan3_k<<<NB, 256, 0, stream>>>(row_ptr, cursor, blk_sums, N);
    scatter_k<<<(E + 255) / 256, 256, 0, stream>>>(src, dst, cursor, csr_src, csr_eid, E);
    compute_c_k<<<1, 384, 0, stream>>>(UW, Ub, cond, cvec);
    cvt_uw_k<<<3 * D_NODE, 384, 0, stream>>>(UW, UWh);
    {
        const int n1 = 3 * GRU3 * D_NODE;
        cvt_f32_k<<<(n1 + 255) / 256, 256, 0, stream>>>(Wih, Wihh, n1);
        cvt_f32_k<<<(n1 + 255) / 256, 256, 0, stream>>>(Whh, Whhh, n1);
    }
    gather_e_k<<<(N + 3) / 4, 256, 0, stream>>>(e, row_ptr, csr_eid, S_e, N);

    float* hout = (float*)d_out;
    const float* hc = h0;
    for (int k = 0; k < 3; ++k) {
        gather_h_k<<<(N + 3) / 4, 256, 0, stream>>>(hc, row_ptr, csr_src, S_h, N);
        node_update<<<(N + ROWS_BLK - 1) / ROWS_BLK, 256, 0, stream>>>(
            hc, S_h, S_e, row_ptr, cvec + k * D_NODE,
            UWh  + (size_t)k * D_NODE * D_IN_P,
            Wihh + (size_t)k * GRU3 * D_NODE,
            Whhh + (size_t)k * GRU3 * D_NODE,
            bih + (size_t)k * GRU3,
            bhh + (size_t)k * GRU3,
            hout, N);   // in-place safe: each block reads/writes only its own rows
        hc = hout;
    }
}

// Round 6
// 706.892 us; speedup vs baseline: 1.5509x; 1.2447x over previous
//
#include <hip/hip_runtime.h>
#include <hip/hip_bf16.h>
#include <hip/hip_fp16.h>

// GGM encode, decomposed (inputs/outputs fp32; internal MFMA in fp16, fp32 accum):
//   agg[v] = deg(v)*(U1 h_v + c_k) + U2*S_h[v] + U3*S_e[v]
//   S_h[v] = sum_{e: dst=v} h[src_e]   (per round, CSR gather, fp32 acc -> fp16)
//   S_e[v] = sum_{e: dst=v} e_e        (once)
//   c_k    = U4 cond + U_b             (once, fp32 exact)
// then GRU: gi = agg@Wih^T + bih, gh = h@Whh^T + bhh, fused elementwise in fp32.
// R5->R6: occupancy fix. 88KB LDS staging killed occupancy (1 wave/SIMD -> pure
// latency-bound, 206us). Now: A-fragments (h, S_h, S_e) live in REGISTERS, only
// agg transposes through LDS (35KB) -> ~3 waves/SIMD, 3x latency hiding.

#define D_NODE 128
#define D_EDGE 64
#define D_IN   322
#define D_IN_P 336   // padded fp16 row stride for U_W (16B-aligned fragment loads)
#define GRU3   384
#define ROWS_BLK 128

typedef _Float16 f16x8 __attribute__((ext_vector_type(8)));
typedef float    f32x4 __attribute__((ext_vector_type(4)));
typedef unsigned short u16x8 __attribute__((ext_vector_type(8)));

__device__ __forceinline__ f16x8 as_f16x8(u16x8 v) { return __builtin_bit_cast(f16x8, v); }
__device__ __forceinline__ f16x8 cvt8(const float* __restrict__ p) {
    const f32x4 u = *(const f32x4*)p;
    const f32x4 v = *(const f32x4*)(p + 4);
    f16x8 r;
    r[0] = (_Float16)u[0]; r[1] = (_Float16)u[1]; r[2] = (_Float16)u[2]; r[3] = (_Float16)u[3];
    r[4] = (_Float16)v[0]; r[5] = (_Float16)v[1]; r[6] = (_Float16)v[2]; r[7] = (_Float16)v[3];
    return r;
}
__device__ __forceinline__ float sigm_(float x) { return 1.f / (1.f + __expf(-x)); }
__device__ __forceinline__ float tanh_(float x) { return 1.f - 2.f / (__expf(2.f * x) + 1.f); }

// ---------------- CSR build ----------------
__global__ void hist_k(const int* __restrict__ dst, int* __restrict__ cnt, int E) {
    int t = blockIdx.x * 256 + threadIdx.x;
    if (t < E) atomicAdd(&cnt[dst[t]], 1);
}

__global__ __launch_bounds__(256) void scan1_k(const int* __restrict__ cnt, int* __restrict__ row_ptr,
                                               int* __restrict__ blk_sums, int N) {
    __shared__ int s[256];
    const int t = threadIdx.x;
    const int base = blockIdx.x * 1024 + t * 4;
    int v0 = (base + 0 < N) ? cnt[base + 0] : 0;
    int v1 = (base + 1 < N) ? cnt[base + 1] : 0;
    int v2 = (base + 2 < N) ? cnt[base + 2] : 0;
    int v3 = (base + 3 < N) ? cnt[base + 3] : 0;
    const int tot = v0 + v1 + v2 + v3;
    s[t] = tot;
    __syncthreads();
    for (int off = 1; off < 256; off <<= 1) {
        int u = (t >= off) ? s[t - off] : 0;
        __syncthreads();
        s[t] += u;
        __syncthreads();
    }
    const int excl = s[t] - tot;
    if (base + 0 < N) row_ptr[base + 0] = excl;
    if (base + 1 < N) row_ptr[base + 1] = excl + v0;
    if (base + 2 < N) row_ptr[base + 2] = excl + v0 + v1;
    if (base + 3 < N) row_ptr[base + 3] = excl + v0 + v1 + v2;
    if (t == 255) blk_sums[blockIdx.x] = s[255];
}

__global__ __launch_bounds__(256) void scan2_k(int* __restrict__ blk_sums, int NB,
                                               int* __restrict__ row_ptr, int N, int E) {
    __shared__ int s[256];
    const int t = threadIdx.x;
    const int v = (t < NB) ? blk_sums[t] : 0;
    s[t] = v;
    __syncthreads();
    for (int off = 1; off < 256; off <<= 1) {
        int u = (t >= off) ? s[t - off] : 0;
        __syncthreads();
        s[t] += u;
        __syncthreads();
    }
    if (t < NB) blk_sums[t] = s[t] - v;
    if (t == 0) row_ptr[N] = E;
}

__global__ __launch_bounds__(256) void scan3_k(int* __restrict__ row_ptr, int* __restrict__ cursor,
                                               const int* __restrict__ blk_sums, int N) {
    const int off = blk_sums[blockIdx.x];
    const int base = blockIdx.x * 1024 + threadIdx.x * 4;
#pragma unroll
    for (int j = 0; j < 4; ++j) {
        const int i = base + j;
        if (i < N) {
            const int v = row_ptr[i] + off;
            row_ptr[i] = v;
            cursor[i] = v;
        }
    }
}

__global__ void scatter_k(const int* __restrict__ src, const int* __restrict__ dst,
                          int* __restrict__ cursor, int* __restrict__ csr_src,
                          int* __restrict__ csr_eid, int E) {
    int t = blockIdx.x * 256 + threadIdx.x;
    if (t < E) {
        int d = dst[t];
        int pos = atomicAdd(&cursor[d], 1);
        csr_src[pos] = src[t];
        csr_eid[pos] = t;
    }
}

// ---------------- weight converts (fp32 -> fp16, once per launch) ----------------
__global__ __launch_bounds__(384) void cvt_uw_k(const float* __restrict__ in, _Float16* __restrict__ out) {
    const int row = blockIdx.x;
    const int t = threadIdx.x;
    if (t < D_IN_P)
        out[row * D_IN_P + t] = (_Float16)(t < D_IN ? in[row * D_IN + t] : 0.f);
}

__global__ void cvt_f32_k(const float* __restrict__ in, _Float16* __restrict__ out, int n) {
    int t = blockIdx.x * 256 + threadIdx.x;
    if (t < n) out[t] = (_Float16)in[t];
}

// ---------------- c_k = U4*cond + U_b (fp32 exact) ----------------
__global__ void compute_c_k(const float* __restrict__ UW, const float* __restrict__ Ub,
                            const float* __restrict__ cond, float* __restrict__ cvec) {
    int t = threadIdx.x;
    if (t < 3 * D_NODE) {
        int k = t >> 7, i = t & 127;
        const float* u = UW + (size_t)k * D_NODE * D_IN + (size_t)i * D_IN + 320;
        cvec[t] = u[0] * cond[0] + u[1] * cond[1] + Ub[k * D_NODE + i];
    }
}

// ---------------- segment sums (CSR gather, wave per node; fp32 acc -> fp16) ----------------
__global__ __launch_bounds__(256) void gather_e_k(const float* __restrict__ e,
                                                  const int* __restrict__ row_ptr,
                                                  const int* __restrict__ csr_eid,
                                                  _Float16* __restrict__ S_e, int N) {
    const int wave = threadIdx.x >> 6, lane = threadIdx.x & 63;
    const int n = blockIdx.x * 4 + wave;
    if (n >= N) return;
    const int p1 = row_ptr[n + 1];
    float a0 = 0.f;
    for (int p = row_ptr[n]; p < p1; ++p) {
        const int eid = csr_eid[p];
        a0 += e[(size_t)eid * D_EDGE + lane];
    }
    S_e[(size_t)n * D_EDGE + lane] = (_Float16)a0;
}

__global__ __launch_bounds__(256) void gather_h_k(const float* __restrict__ h_cur,
                                                  const int* __restrict__ row_ptr,
                                                  const int* __restrict__ csr_src,
                                                  _Float16* __restrict__ S_h, int N) {
    const int wave = threadIdx.x >> 6, lane = threadIdx.x & 63;
    const int n = blockIdx.x * 4 + wave;
    if (n >= N) return;
    const int p1 = row_ptr[n + 1];
    float a0 = 0.f, a1 = 0.f;
    for (int p = row_ptr[n]; p < p1; ++p) {
        const int s = csr_src[p];
        a0 += h_cur[(size_t)s * D_NODE + lane];
        a1 += h_cur[(size_t)s * D_NODE + 64 + lane];
    }
    S_h[(size_t)n * D_NODE + lane] = (_Float16)a0;
    S_h[(size_t)n * D_NODE + 64 + lane] = (_Float16)a1;
}

// ---------------- fused node update (MFMA fp16), v3 ----------------
// Block = 256 thr (4 waves), 128 rows/block; wave w owns rows w*32..w*32+31 (2 m-tiles).
// All A-fragments (h, S_h, S_e) register-resident, loaded ONCE up front (deep load
// pipeline, no LDS staging). Only agg transposes through LDS (C-layout -> A-layout).
// nb-outer: each B fragment load feeds 2 MFMAs.
__global__ __launch_bounds__(256) void node_update(
    const float* __restrict__ h_cur,
    const _Float16* __restrict__ S_h,
    const _Float16* __restrict__ S_e,
    const int* __restrict__ row_ptr,
    const float* __restrict__ cvec,
    const _Float16* __restrict__ UWh,   // [128][336] fp16, this round's slice
    const _Float16* __restrict__ Wihh,  // [384][128] fp16
    const _Float16* __restrict__ Whhh,  // [384][128] fp16
    const float* __restrict__ bih,
    const float* __restrict__ bhh,
    float* __restrict__ h_next,
    int N) {
    __shared__ __align__(16) _Float16 lds_agg[ROWS_BLK][136];  // 35 KB -> 3-4 blocks/CU

    const int tid  = threadIdx.x;
    const int row0 = blockIdx.x * ROWS_BLK;
    const int wave = tid >> 6;
    const int lane = tid & 63;
    const int l15  = lane & 15;
    const int lg   = lane >> 4;
    const int wrow = wave * 32;          // wave's first row within block
    const int rbase = row0 + wrow;       // global

    const unsigned short* uw  = (const unsigned short*)UWh;
    const unsigned short* wih = (const unsigned short*)Wihh;
    const unsigned short* whh = (const unsigned short*)Whhh;
    const unsigned short* shp = (const unsigned short*)S_h;
    const unsigned short* sep = (const unsigned short*)S_e;

    // ---- all A-fragments into registers (independent loads -> deep pipeline) ----
    f16x8 a_h[2][4];   // h
    f16x8 a_sh[2][4];  // S_h
    f16x8 a_se[2][2];  // S_e
#pragma unroll
    for (int m = 0; m < 2; ++m) {
        const int arow = min(rbase + m * 16 + l15, N - 1);
#pragma unroll
        for (int kb = 0; kb < 4; ++kb) {
            a_h[m][kb]  = cvt8(h_cur + (size_t)arow * D_NODE + kb * 32 + lg * 8);
            a_sh[m][kb] = as_f16x8(*(const u16x8*)(shp + (size_t)arow * D_NODE + kb * 32 + lg * 8));
        }
#pragma unroll
        for (int kb = 0; kb < 2; ++kb)
            a_se[m][kb] = as_f16x8(*(const u16x8*)(sep + (size_t)arow * D_EDGE + kb * 32 + lg * 8));
    }

    // deg in C-layout (rows lg*4+i within each m-tile)
    float degv[2][4];
#pragma unroll
    for (int m = 0; m < 2; ++m)
#pragma unroll
        for (int i = 0; i < 4; ++i) {
            const int n = min(rbase + m * 16 + lg * 4 + i, N - 1);
            degv[m][i] = (float)(row_ptr[n + 1] - row_ptr[n]);
        }

    // ---- Phase 1: agg = deg*(U1 h + c) + U2 S_h + U3 S_e, per output col-block nb ----
#pragma unroll 1
    for (int nb = 0; nb < 8; ++nb) {
        const int col = nb * 16 + l15;
        f32x4 acc1[2] = {{0.f,0.f,0.f,0.f},{0.f,0.f,0.f,0.f}};
        f32x4 acc2[2] = {{0.f,0.f,0.f,0.f},{0.f,0.f,0.f,0.f}};
#pragma unroll
        for (int kb = 0; kb < 4; ++kb) {   // U1: A = h
            f16x8 b = as_f16x8(*(const u16x8*)(uw + (size_t)col * D_IN_P + kb * 32 + lg * 8));
            acc1[0] = __builtin_amdgcn_mfma_f32_16x16x32_f16(a_h[0][kb], b, acc1[0], 0, 0, 0);
            acc1[1] = __builtin_amdgcn_mfma_f32_16x16x32_f16(a_h[1][kb], b, acc1[1], 0, 0, 0);
        }
#pragma unroll
        for (int kb = 0; kb < 4; ++kb) {   // U2: A = S_h
            f16x8 b = as_f16x8(*(const u16x8*)(uw + (size_t)col * D_IN_P + 128 + kb * 32 + lg * 8));
            acc2[0] = __builtin_amdgcn_mfma_f32_16x16x32_f16(a_sh[0][kb], b, acc2[0], 0, 0, 0);
            acc2[1] = __builtin_amdgcn_mfma_f32_16x16x32_f16(a_sh[1][kb], b, acc2[1], 0, 0, 0);
        }
#pragma unroll
        for (int kb = 0; kb < 2; ++kb) {   // U3: A = S_e
            f16x8 b = as_f16x8(*(const u16x8*)(uw + (size_t)col * D_IN_P + 256 + kb * 32 + lg * 8));
            acc2[0] = __builtin_amdgcn_mfma_f32_16x16x32_f16(a_se[0][kb], b, acc2[0], 0, 0, 0);
            acc2[1] = __builtin_amdgcn_mfma_f32_16x16x32_f16(a_se[1][kb], b, acc2[1], 0, 0, 0);
        }
        const float cv = cvec[col];
#pragma unroll
        for (int m = 0; m < 2; ++m)
#pragma unroll
            for (int i = 0; i < 4; ++i) {
                const float aggv = degv[m][i] * (acc1[m][i] + cv) + acc2[m][i];
                lds_agg[wrow + m * 16 + lg * 4 + i][nb * 16 + l15] = (_Float16)aggv;
            }
    }
    __syncthreads();   // agg C-layout -> A-layout visibility (cross-lane)

    // agg A-frags into registers once (replaces a_sh/a_se register budget)
    f16x8 a_agg[2][4];
#pragma unroll
    for (int m = 0; m < 2; ++m)
#pragma unroll
        for (int kb = 0; kb < 4; ++kb)
            a_agg[m][kb] = as_f16x8(*(const u16x8*)&lds_agg[wrow + m * 16 + l15][kb * 32 + lg * 8]);

    // ---- Phase 2: GRU gates, per output col-block nb ----
#pragma unroll 1
    for (int nb = 0; nb < 8; ++nb) {
        const int c0 = nb * 16 + l15;
        f32x4 air[2] = {{0.f,0.f,0.f,0.f},{0.f,0.f,0.f,0.f}};
        f32x4 aiz[2] = {{0.f,0.f,0.f,0.f},{0.f,0.f,0.f,0.f}};
        f32x4 ain_[2] = {{0.f,0.f,0.f,0.f},{0.f,0.f,0.f,0.f}};
        f32x4 ahr[2] = {{0.f,0.f,0.f,0.f},{0.f,0.f,0.f,0.f}};
        f32x4 ahz[2] = {{0.f,0.f,0.f,0.f},{0.f,0.f,0.f,0.f}};
        f32x4 ahn[2] = {{0.f,0.f,0.f,0.f},{0.f,0.f,0.f,0.f}};
#pragma unroll
        for (int kb = 0; kb < 4; ++kb) {
            f16x8 b;
            b = as_f16x8(*(const u16x8*)(wih + (size_t)(c0)       * D_NODE + kb * 32 + lg * 8));
            air[0] = __builtin_amdgcn_mfma_f32_16x16x32_f16(a_agg[0][kb], b, air[0], 0, 0, 0);
            air[1] = __builtin_amdgcn_mfma_f32_16x16x32_f16(a_agg[1][kb], b, air[1], 0, 0, 0);
            b = as_f16x8(*(const u16x8*)(wih + (size_t)(c0 + 128) * D_NODE + kb * 32 + lg * 8));
            aiz[0] = __builtin_amdgcn_mfma_f32_16x16x32_f16(a_agg[0][kb], b, aiz[0], 0, 0, 0);
            aiz[1] = __builtin_amdgcn_mfma_f32_16x16x32_f16(a_agg[1][kb], b, aiz[1], 0, 0, 0);
            b = as_f16x8(*(const u16x8*)(wih + (size_t)(c0 + 256) * D_NODE + kb * 32 + lg * 8));
            ain_[0] = __builtin_amdgcn_mfma_f32_16x16x32_f16(a_agg[0][kb], b, ain_[0], 0, 0, 0);
            ain_[1] = __builtin_amdgcn_mfma_f32_16x16x32_f16(a_agg[1][kb], b, ain_[1], 0, 0, 0);
            b = as_f16x8(*(const u16x8*)(whh + (size_t)(c0)       * D_NODE + kb * 32 + lg * 8));
            ahr[0] = __builtin_amdgcn_mfma_f32_16x16x32_f16(a_h[0][kb], b, ahr[0], 0, 0, 0);
            ahr[1] = __builtin_amdgcn_mfma_f32_16x16x32_f16(a_h[1][kb], b, ahr[1], 0, 0, 0);
            b = as_f16x8(*(const u16x8*)(whh + (size_t)(c0 + 128) * D_NODE + kb * 32 + lg * 8));
            ahz[0] = __builtin_amdgcn_mfma_f32_16x16x32_f16(a_h[0][kb], b, ahz[0], 0, 0, 0);
            ahz[1] = __builtin_amdgcn_mfma_f32_16x16x32_f16(a_h[1][kb], b, ahz[1], 0, 0, 0);
            b = as_f16x8(*(const u16x8*)(whh + (size_t)(c0 + 256) * D_NODE + kb * 32 + lg * 8));
            ahn[0] = __builtin_amdgcn_mfma_f32_16x16x32_f16(a_h[0][kb], b, ahn[0], 0, 0, 0);
            ahn[1] = __builtin_amdgcn_mfma_f32_16x16x32_f16(a_h[1][kb], b, ahn[1], 0, 0, 0);
        }
        const int d = c0;
        const float bir = bih[d],  biz = bih[128 + d], bin = bih[256 + d];
        const float bhr = bhh[d],  bhz = bhh[128 + d], bhn = bhh[256 + d];
#pragma unroll
        for (int m = 0; m < 2; ++m)
#pragma unroll
            for (int i = 0; i < 4; ++i) {
                const int n = rbase + m * 16 + lg * 4 + i;
                if (n < N) {
                    const float r  = sigm_(air[m][i] + bir + ahr[m][i] + bhr);
                    const float z  = sigm_(aiz[m][i] + biz + ahz[m][i] + bhz);
                    const float nn = tanh_(ain_[m][i] + bin + r * (ahn[m][i] + bhn));
                    const float hv = h_cur[(size_t)n * D_NODE + d];
                    h_next[(size_t)n * D_NODE + d] = (1.f - z) * nn + z * hv;
                }
            }
    }
}

// ---------------- launch ----------------
extern "C" void kernel_launch(void* const* d_in, const int* in_sizes, int n_in,
                              void* d_out, int out_size, void* d_ws, size_t ws_size,
                              hipStream_t stream) {
    const float* h0   = (const float*)d_in[0];
    const float* e    = (const float*)d_in[1];
    const int*   src  = (const int*)d_in[2];
    const int*   dst  = (const int*)d_in[3];
    const float* cond = (const float*)d_in[4];
    const float* UW   = (const float*)d_in[5];
    const float* Ub   = (const float*)d_in[6];
    const float* Wih  = (const float*)d_in[7];
    const float* Whh  = (const float*)d_in[8];
    const float* bih  = (const float*)d_in[9];
    const float* bhh  = (const float*)d_in[10];

    const int N = in_sizes[0] / D_NODE;
    const int E = in_sizes[2];
    const int NB = (N + 1023) / 1024;   // scan blocks (<= 256)

    char* wsb = (char*)d_ws;
    size_t off = 0;
    auto carve = [&](size_t bytes) -> char* {
        char* p = wsb + off;
        off = (off + bytes + 255) & ~(size_t)255;
        return p;
    };
    int*   cnt      = (int*)carve((size_t)N * 4);
    int*   row_ptr  = (int*)carve(((size_t)N + 1) * 4);
    int*   cursor   = (int*)carve((size_t)N * 4);
    int*   csr_src  = (int*)carve((size_t)E * 4);
    int*   csr_eid  = (int*)carve((size_t)E * 4);
    int*   blk_sums = (int*)carve(256 * 4);
    float* cvec     = (float*)carve(3 * D_NODE * 4);
    _Float16* S_e  = (_Float16*)carve((size_t)N * D_EDGE * 2);
    _Float16* S_h  = (_Float16*)carve((size_t)N * D_NODE * 2);
    _Float16* UWh  = (_Float16*)carve((size_t)3 * D_NODE * D_IN_P * 2);
    _Float16* Wihh = (_Float16*)carve((size_t)3 * GRU3 * D_NODE * 2);
    _Float16* Whhh = (_Float16*)carve((size_t)3 * GRU3 * D_NODE * 2);
    (void)ws_size; (void)n_in; (void)out_size;

    hipMemsetAsync(cnt, 0, (size_t)N * 4, stream);
    hist_k<<<(E + 255) / 256, 256, 0, stream>>>(dst, cnt, E);
    scan1_k<<<NB, 256, 0, stream>>>(cnt, row_ptr, blk_sums, N);
    scan2_k<<<1, 256, 0, stream>>>(blk_sums, NB, row_ptr, N, E);
    scan3_k<<<NB, 256, 0, stream>>>(row_ptr, cursor, blk_sums, N);
    scatter_k<<<(E + 255) / 256, 256, 0, stream>>>(src, dst, cursor, csr_src, csr_eid, E);
    compute_c_k<<<1, 384, 0, stream>>>(UW, Ub, cond, cvec);
    cvt_uw_k<<<3 * D_NODE, 384, 0, stream>>>(UW, UWh);
    {
        const int n1 = 3 * GRU3 * D_NODE;
        cvt_f32_k<<<(n1 + 255) / 256, 256, 0, stream>>>(Wih, Wihh, n1);
        cvt_f32_k<<<(n1 + 255) / 256, 256, 0, stream>>>(Whh, Whhh, n1);
    }
    gather_e_k<<<(N + 3) / 4, 256, 0, stream>>>(e, row_ptr, csr_eid, S_e, N);

    float* hout = (float*)d_out;
    const float* hc = h0;
    for (int k = 0; k < 3; ++k) {
        gather_h_k<<<(N + 3) / 4, 256, 0, stream>>>(hc, row_ptr, csr_src, S_h, N);
        node_update<<<(N + ROWS_BLK - 1) / ROWS_BLK, 256, 0, stream>>>(
            hc, S_h, S_e, row_ptr, cvec + k * D_NODE,
            UWh  + (size_t)k * D_NODE * D_IN_P,
            Wihh + (size_t)k * GRU3 * D_NODE,
            Whhh + (size_t)k * GRU3 * D_NODE,
            bih + (size_t)k * GRU3,
            bhh + (size_t)k * GRU3,
            hout, N);   // in-place safe: each block reads/writes only its own rows
        hc = hout;
    }
}

// Round 7
// 633.776 us; speedup vs baseline: 1.7298x; 1.1154x over previous
//
#include <hip/hip_runtime.h>
#include <hip/hip_bf16.h>
#include <hip/hip_fp16.h>

// GGM encode, decomposed (inputs/outputs fp32; internal MFMA in fp16, fp32 accum):
//   agg[v] = deg(v)*(U1 h_v + c_k) + U2*S_h[v] + U3*S_e[v]
//   GRU: gi = agg@Wih^T + bih, gh = h@Whh^T + bhh, fused elementwise in fp32.
// R6->R7: node_update split into agg_k + gru_k with DOUBLE-BUFFERED LDS WEIGHT PANELS
// (reg-staged, padded strides 656B/272B == 16 mod 128 -> contiguous-equivalent banking).
// Kills the per-wave L2 B-fragment latency serialization (R6: 100 VGPR capped in-flight
// loads; MfmaUtil 7%, 950 GB/s). agg round-trips via global fp16 (25.6MB, ~8us).

#define D_NODE 128
#define D_EDGE 64
#define D_IN   322
#define GRU3   384
#define ROWS_BLK 128
#define PA_STRIDE 328   // panel-A row stride (elems): 656B = 16 mod 128 -> conflict-free
#define PB_STRIDE 136   // panel-B row stride (elems): 272B = 16 mod 128 -> conflict-free

typedef _Float16 f16x8 __attribute__((ext_vector_type(8)));
typedef float    f32x4 __attribute__((ext_vector_type(4)));
typedef unsigned short u16x8 __attribute__((ext_vector_type(8)));

__device__ __forceinline__ f16x8 as_f16x8(u16x8 v) { return __builtin_bit_cast(f16x8, v); }
__device__ __forceinline__ f16x8 cvt8(const float* __restrict__ p) {
    const f32x4 u = *(const f32x4*)p;
    const f32x4 v = *(const f32x4*)(p + 4);
    f16x8 r;
    r[0] = (_Float16)u[0]; r[1] = (_Float16)u[1]; r[2] = (_Float16)u[2]; r[3] = (_Float16)u[3];
    r[4] = (_Float16)v[0]; r[5] = (_Float16)v[1]; r[6] = (_Float16)v[2]; r[7] = (_Float16)v[3];
    return r;
}
__device__ __forceinline__ float sigm_(float x) { return 1.f / (1.f + __expf(-x)); }
__device__ __forceinline__ float tanh_(float x) { return 1.f - 2.f / (__expf(2.f * x) + 1.f); }

// ---------------- CSR build ----------------
__global__ void hist_k(const int* __restrict__ dst, int* __restrict__ cnt, int E) {
    int t = blockIdx.x * 256 + threadIdx.x;
    if (t < E) atomicAdd(&cnt[dst[t]], 1);
}

__global__ __launch_bounds__(256) void scan1_k(const int* __restrict__ cnt, int* __restrict__ row_ptr,
                                               int* __restrict__ blk_sums, int N) {
    __shared__ int s[256];
    const int t = threadIdx.x;
    const int base = blockIdx.x * 1024 + t * 4;
    int v0 = (base + 0 < N) ? cnt[base + 0] : 0;
    int v1 = (base + 1 < N) ? cnt[base + 1] : 0;
    int v2 = (base + 2 < N) ? cnt[base + 2] : 0;
    int v3 = (base + 3 < N) ? cnt[base + 3] : 0;
    const int tot = v0 + v1 + v2 + v3;
    s[t] = tot;
    __syncthreads();
    for (int off = 1; off < 256; off <<= 1) {
        int u = (t >= off) ? s[t - off] : 0;
        __syncthreads();
        s[t] += u;
        __syncthreads();
    }
    const int excl = s[t] - tot;
    if (base + 0 < N) row_ptr[base + 0] = excl;
    if (base + 1 < N) row_ptr[base + 1] = excl + v0;
    if (base + 2 < N) row_ptr[base + 2] = excl + v0 + v1;
    if (base + 3 < N) row_ptr[base + 3] = excl + v0 + v1 + v2;
    if (t == 255) blk_sums[blockIdx.x] = s[255];
}

__global__ __launch_bounds__(256) void scan2_k(int* __restrict__ blk_sums, int NB,
                                               int* __restrict__ row_ptr, int N, int E) {
    __shared__ int s[256];
    const int t = threadIdx.x;
    const int v = (t < NB) ? blk_sums[t] : 0;
    s[t] = v;
    __syncthreads();
    for (int off = 1; off < 256; off <<= 1) {
        int u = (t >= off) ? s[t - off] : 0;
        __syncthreads();
        s[t] += u;
        __syncthreads();
    }
    if (t < NB) blk_sums[t] = s[t] - v;
    if (t == 0) row_ptr[N] = E;
}

__global__ __launch_bounds__(256) void scan3_k(int* __restrict__ row_ptr, int* __restrict__ cursor,
                                               const int* __restrict__ blk_sums, int N) {
    const int off = blk_sums[blockIdx.x];
    const int base = blockIdx.x * 1024 + threadIdx.x * 4;
#pragma unroll
    for (int j = 0; j < 4; ++j) {
        const int i = base + j;
        if (i < N) {
            const int v = row_ptr[i] + off;
            row_ptr[i] = v;
            cursor[i] = v;
        }
    }
}

__global__ void scatter_k(const int* __restrict__ src, const int* __restrict__ dst,
                          int* __restrict__ cursor, int* __restrict__ csr_src,
                          int* __restrict__ csr_eid, int E) {
    int t = blockIdx.x * 256 + threadIdx.x;
    if (t < E) {
        int d = dst[t];
        int pos = atomicAdd(&cursor[d], 1);
        csr_src[pos] = src[t];
        csr_eid[pos] = t;
    }
}

// ---------------- weight converts (fp32 -> fp16, once per launch) ----------------
// U_W: [384 rows][322] fp32 -> trimmed packed [384 rows][320] fp16 (cond cols -> cvec)
__global__ __launch_bounds__(320) void cvt_uwp_k(const float* __restrict__ in, _Float16* __restrict__ out) {
    const int row = blockIdx.x;   // 0..383
    const int t = threadIdx.x;    // 0..319
    out[(size_t)row * 320 + t] = (_Float16)in[(size_t)row * D_IN + t];
}

__global__ void cvt_f32_k(const float* __restrict__ in, _Float16* __restrict__ out, int n) {
    int t = blockIdx.x * 256 + threadIdx.x;
    if (t < n) out[t] = (_Float16)in[t];
}

// ---------------- c_k = U4*cond + U_b (fp32 exact) ----------------
__global__ void compute_c_k(const float* __restrict__ UW, const float* __restrict__ Ub,
                            const float* __restrict__ cond, float* __restrict__ cvec) {
    int t = threadIdx.x;
    if (t < 3 * D_NODE) {
        int k = t >> 7, i = t & 127;
        const float* u = UW + (size_t)k * D_NODE * D_IN + (size_t)i * D_IN + 320;
        cvec[t] = u[0] * cond[0] + u[1] * cond[1] + Ub[k * D_NODE + i];
    }
}

// ---------------- segment sums (CSR gather, wave per node; fp32 acc -> fp16) ----------------
__global__ __launch_bounds__(256) void gather_e_k(const float* __restrict__ e,
                                                  const int* __restrict__ row_ptr,
                                                  const int* __restrict__ csr_eid,
                                                  _Float16* __restrict__ S_e, int N) {
    const int wave = threadIdx.x >> 6, lane = threadIdx.x & 63;
    const int n = blockIdx.x * 4 + wave;
    if (n >= N) return;
    const int p1 = row_ptr[n + 1];
    float a0 = 0.f;
    for (int p = row_ptr[n]; p < p1; ++p) {
        const int eid = csr_eid[p];
        a0 += e[(size_t)eid * D_EDGE + lane];
    }
    S_e[(size_t)n * D_EDGE + lane] = (_Float16)a0;
}

__global__ __launch_bounds__(256) void gather_h_k(const float* __restrict__ h_cur,
                                                  const int* __restrict__ row_ptr,
                                                  const int* __restrict__ csr_src,
                                                  _Float16* __restrict__ S_h, int N) {
    const int wave = threadIdx.x >> 6, lane = threadIdx.x & 63;
    const int n = blockIdx.x * 4 + wave;
    if (n >= N) return;
    const int p1 = row_ptr[n + 1];
    float a0 = 0.f, a1 = 0.f;
    for (int p = row_ptr[n]; p < p1; ++p) {
        const int s = csr_src[p];
        a0 += h_cur[(size_t)s * D_NODE + lane];
        a1 += h_cur[(size_t)s * D_NODE + 64 + lane];
    }
    S_h[(size_t)n * D_NODE + lane] = (_Float16)a0;
    S_h[(size_t)n * D_NODE + 64 + lane] = (_Float16)a1;
}

// ---------------- agg kernel: agg = deg*(U1 h + c) + U2 S_h + U3 S_e ----------------
// 128 rows/block, 4 waves x 32 rows (m=2). Per output col-block nb: B-panel (U' rows
// nb*16..+15, K=320) double-buffered in LDS; panel nb+1 loads issued before nb compute.
__global__ __launch_bounds__(256) void agg_k(
    const float* __restrict__ h_cur,
    const _Float16* __restrict__ S_h,
    const _Float16* __restrict__ S_e,
    const int* __restrict__ row_ptr,
    const float* __restrict__ cvec,
    const _Float16* __restrict__ UWp,   // [128][320] fp16, this round's slice
    _Float16* __restrict__ agg,
    int N) {
    __shared__ __align__(16) _Float16 pbuf[2][16 * PA_STRIDE];  // 2 x 10.5 KB

    const int tid  = threadIdx.x;
    const int wave = tid >> 6;
    const int lane = tid & 63;
    const int l15  = lane & 15;
    const int lg   = lane >> 4;
    const int rbase = blockIdx.x * ROWS_BLK + wave * 32;

    const unsigned short* shp = (const unsigned short*)S_h;
    const unsigned short* sep = (const unsigned short*)S_e;
    const unsigned short* uwp = (const unsigned short*)UWp;

    // A-fragments in registers
    f16x8 a_h[2][4], a_sh[2][4], a_se[2][2];
#pragma unroll
    for (int m = 0; m < 2; ++m) {
        const int arow = min(rbase + m * 16 + l15, N - 1);
#pragma unroll
        for (int kb = 0; kb < 4; ++kb) {
            a_h[m][kb]  = cvt8(h_cur + (size_t)arow * D_NODE + kb * 32 + lg * 8);
            a_sh[m][kb] = as_f16x8(*(const u16x8*)(shp + (size_t)arow * D_NODE + kb * 32 + lg * 8));
        }
#pragma unroll
        for (int kb = 0; kb < 2; ++kb)
            a_se[m][kb] = as_f16x8(*(const u16x8*)(sep + (size_t)arow * D_EDGE + kb * 32 + lg * 8));
    }
    float degv[2][4];
#pragma unroll
    for (int m = 0; m < 2; ++m)
#pragma unroll
        for (int i = 0; i < 4; ++i) {
            const int n = min(rbase + m * 16 + lg * 4 + i, N - 1);
            degv[m][i] = (float)(row_ptr[n + 1] - row_ptr[n]);
        }

    // panel staging (reg round-trip; 640 16B-chunks per panel, 3 rounds of 256 thr)
    u16x8 pr0, pr1, pr2;
    auto load_panel = [&](int nb) {
        const int c0 = tid, c1 = 256 + tid, c2 = 512 + tid;
        pr0 = *(const u16x8*)(uwp + (size_t)(nb * 16 + c0 / 40) * 320 + (c0 % 40) * 8);
        pr1 = *(const u16x8*)(uwp + (size_t)(nb * 16 + c1 / 40) * 320 + (c1 % 40) * 8);
        if (c2 < 640)
            pr2 = *(const u16x8*)(uwp + (size_t)(nb * 16 + c2 / 40) * 320 + (c2 % 40) * 8);
    };
    auto write_panel = [&](int b) {
        const int c0 = tid, c1 = 256 + tid, c2 = 512 + tid;
        *(u16x8*)&pbuf[b][(c0 / 40) * PA_STRIDE + (c0 % 40) * 8] = pr0;
        *(u16x8*)&pbuf[b][(c1 / 40) * PA_STRIDE + (c1 % 40) * 8] = pr1;
        if (c2 < 640)
            *(u16x8*)&pbuf[b][(c2 / 40) * PA_STRIDE + (c2 % 40) * 8] = pr2;
    };

    load_panel(0);
    write_panel(0);
    __syncthreads();

#pragma unroll 1
    for (int nb = 0; nb < 8; ++nb) {
        if (nb < 7) load_panel(nb + 1);            // issue early, consume after compute
        const _Float16* bp = pbuf[nb & 1];
        f32x4 acc1[2] = {{0.f,0.f,0.f,0.f},{0.f,0.f,0.f,0.f}};
        f32x4 acc2[2] = {{0.f,0.f,0.f,0.f},{0.f,0.f,0.f,0.f}};
#pragma unroll
        for (int kb = 0; kb < 10; ++kb) {
            f16x8 b = as_f16x8(*(const u16x8*)&bp[l15 * PA_STRIDE + kb * 32 + lg * 8]);
            if (kb < 4) {
                acc1[0] = __builtin_amdgcn_mfma_f32_16x16x32_f16(a_h[0][kb], b, acc1[0], 0, 0, 0);
                acc1[1] = __builtin_amdgcn_mfma_f32_16x16x32_f16(a_h[1][kb], b, acc1[1], 0, 0, 0);
            } else if (kb < 8) {
                acc2[0] = __builtin_amdgcn_mfma_f32_16x16x32_f16(a_sh[0][kb-4], b, acc2[0], 0, 0, 0);
                acc2[1] = __builtin_amdgcn_mfma_f32_16x16x32_f16(a_sh[1][kb-4], b, acc2[1], 0, 0, 0);
            } else {
                acc2[0] = __builtin_amdgcn_mfma_f32_16x16x32_f16(a_se[0][kb-8], b, acc2[0], 0, 0, 0);
                acc2[1] = __builtin_amdgcn_mfma_f32_16x16x32_f16(a_se[1][kb-8], b, acc2[1], 0, 0, 0);
            }
        }
        const float cv = cvec[nb * 16 + l15];
#pragma unroll
        for (int m = 0; m < 2; ++m)
#pragma unroll
            for (int i = 0; i < 4; ++i) {
                const int n = rbase + m * 16 + lg * 4 + i;
                if (n < N)
                    agg[(size_t)n * D_NODE + nb * 16 + l15] =
                        (_Float16)(degv[m][i] * (acc1[m][i] + cv) + acc2[m][i]);
            }
        if (nb < 7) write_panel((nb + 1) & 1);
        __syncthreads();
    }
}

// ---------------- GRU kernel: h' = (1-z)*n + z*h ----------------
// Per nb: panel = 6 gate row-groups (wih c0/c0+128/c0+256, whh same) [96][128],
// double-buffered in LDS. A = a_agg (fp16 from agg buf) + a_h (cvt f32). m=2.
__global__ __launch_bounds__(256) void gru_k(
    const float* __restrict__ h_cur,
    const _Float16* __restrict__ agg,
    const _Float16* __restrict__ Wihh,  // [384][128] fp16
    const _Float16* __restrict__ Whhh,  // [384][128] fp16
    const float* __restrict__ bih,
    const float* __restrict__ bhh,
    float* __restrict__ h_next,
    int N) {
    __shared__ __align__(16) _Float16 pbuf[2][96 * PB_STRIDE];  // 2 x 25.5 KB

    const int tid  = threadIdx.x;
    const int wave = tid >> 6;
    const int lane = tid & 63;
    const int l15  = lane & 15;
    const int lg   = lane >> 4;
    const int rbase = blockIdx.x * ROWS_BLK + wave * 32;

    const unsigned short* agp = (const unsigned short*)agg;
    const unsigned short* wih = (const unsigned short*)Wihh;
    const unsigned short* whh = (const unsigned short*)Whhh;

    f16x8 a_ag[2][4], a_h[2][4];
#pragma unroll
    for (int m = 0; m < 2; ++m) {
        const int arow = min(rbase + m * 16 + l15, N - 1);
#pragma unroll
        for (int kb = 0; kb < 4; ++kb) {
            a_ag[m][kb] = as_f16x8(*(const u16x8*)(agp + (size_t)arow * D_NODE + kb * 32 + lg * 8));
            a_h[m][kb]  = cvt8(h_cur + (size_t)arow * D_NODE + kb * 32 + lg * 8);
        }
    }

    // panel staging: 1536 16B-chunks = 6 rounds x 256 thr
    u16x8 pr[6];
    auto load_panel = [&](int nb) {
#pragma unroll
        for (int r = 0; r < 6; ++r) {
            const int c = r * 256 + tid;
            const int row = c >> 4;            // 0..95
            const int off = (c & 15) * 8;      // elems
            const int gate = row >> 4;         // 0..5
            const int col = nb * 16 + (row & 15) + (gate % 3) * D_NODE;
            const unsigned short* mat = (gate < 3) ? wih : whh;
            pr[r] = *(const u16x8*)(mat + (size_t)col * D_NODE + off);
        }
    };
    auto write_panel = [&](int b) {
#pragma unroll
        for (int r = 0; r < 6; ++r) {
            const int c = r * 256 + tid;
            const int row = c >> 4;
            const int off = (c & 15) * 8;
            *(u16x8*)&pbuf[b][row * PB_STRIDE + off] = pr[r];
        }
    };

    load_panel(0);
    write_panel(0);
    __syncthreads();

#pragma unroll 1
    for (int nb = 0; nb < 8; ++nb) {
        if (nb < 7) load_panel(nb + 1);
        const int d = nb * 16 + l15;
        // hv + biases issued early (consumed in epilogue)
        float hv[2][4];
#pragma unroll
        for (int m = 0; m < 2; ++m)
#pragma unroll
            for (int i = 0; i < 4; ++i) {
                const int n = min(rbase + m * 16 + lg * 4 + i, N - 1);
                hv[m][i] = h_cur[(size_t)n * D_NODE + d];
            }
        const float bir = bih[d],       biz = bih[128 + d], bin = bih[256 + d];
        const float bhr = bhh[d],       bhz = bhh[128 + d], bhn = bhh[256 + d];

        const _Float16* bp = pbuf[nb & 1];
        f32x4 air[2] = {{0.f,0.f,0.f,0.f},{0.f,0.f,0.f,0.f}};
        f32x4 aiz[2] = {{0.f,0.f,0.f,0.f},{0.f,0.f,0.f,0.f}};
        f32x4 ain_[2] = {{0.f,0.f,0.f,0.f},{0.f,0.f,0.f,0.f}};
        f32x4 ahr[2] = {{0.f,0.f,0.f,0.f},{0.f,0.f,0.f,0.f}};
        f32x4 ahz[2] = {{0.f,0.f,0.f,0.f},{0.f,0.f,0.f,0.f}};
        f32x4 ahn[2] = {{0.f,0.f,0.f,0.f},{0.f,0.f,0.f,0.f}};
#pragma unroll
        for (int kb = 0; kb < 4; ++kb) {
            const int ko = kb * 32 + lg * 8;
            f16x8 b;
            b = as_f16x8(*(const u16x8*)&bp[(0 * 16 + l15) * PB_STRIDE + ko]);
            air[0] = __builtin_amdgcn_mfma_f32_16x16x32_f16(a_ag[0][kb], b, air[0], 0, 0, 0);
            air[1] = __builtin_amdgcn_mfma_f32_16x16x32_f16(a_ag[1][kb], b, air[1], 0, 0, 0);
            b = as_f16x8(*(const u16x8*)&bp[(1 * 16 + l15) * PB_STRIDE + ko]);
            aiz[0] = __builtin_amdgcn_mfma_f32_16x16x32_f16(a_ag[0][kb], b, aiz[0], 0, 0, 0);
            aiz[1] = __builtin_amdgcn_mfma_f32_16x16x32_f16(a_ag[1][kb], b, aiz[1], 0, 0, 0);
            b = as_f16x8(*(const u16x8*)&bp[(2 * 16 + l15) * PB_STRIDE + ko]);
            ain_[0] = __builtin_amdgcn_mfma_f32_16x16x32_f16(a_ag[0][kb], b, ain_[0], 0, 0, 0);
            ain_[1] = __builtin_amdgcn_mfma_f32_16x16x32_f16(a_ag[1][kb], b, ain_[1], 0, 0, 0);
            b = as_f16x8(*(const u16x8*)&bp[(3 * 16 + l15) * PB_STRIDE + ko]);
            ahr[0] = __builtin_amdgcn_mfma_f32_16x16x32_f16(a_h[0][kb], b, ahr[0], 0, 0, 0);
            ahr[1] = __builtin_amdgcn_mfma_f32_16x16x32_f16(a_h[1][kb], b, ahr[1], 0, 0, 0);
            b = as_f16x8(*(const u16x8*)&bp[(4 * 16 + l15) * PB_STRIDE + ko]);
            ahz[0] = __builtin_amdgcn_mfma_f32_16x16x32_f16(a_h[0][kb], b, ahz[0], 0, 0, 0);
            ahz[1] = __builtin_amdgcn_mfma_f32_16x16x32_f16(a_h[1][kb], b, ahz[1], 0, 0, 0);
            b = as_f16x8(*(const u16x8*)&bp[(5 * 16 + l15) * PB_STRIDE + ko]);
            ahn[0] = __builtin_amdgcn_mfma_f32_16x16x32_f16(a_h[0][kb], b, ahn[0], 0, 0, 0);
            ahn[1] = __builtin_amdgcn_mfma_f32_16x16x32_f16(a_h[1][kb], b, ahn[1], 0, 0, 0);
        }
#pragma unroll
        for (int m = 0; m < 2; ++m)
#pragma unroll
            for (int i = 0; i < 4; ++i) {
                const int n = rbase + m * 16 + lg * 4 + i;
                if (n < N) {
                    const float r  = sigm_(air[m][i] + bir + ahr[m][i] + bhr);
                    const float z  = sigm_(aiz[m][i] + biz + ahz[m][i] + bhz);
                    const float nn = tanh_(ain_[m][i] + bin + r * (ahn[m][i] + bhn));
                    h_next[(size_t)n * D_NODE + d] = (1.f - z) * nn + z * hv[m][i];
                }
            }
        if (nb < 7) write_panel((nb + 1) & 1);
        __syncthreads();
    }
}

// ---------------- launch ----------------
extern "C" void kernel_launch(void* const* d_in, const int* in_sizes, int n_in,
                              void* d_out, int out_size, void* d_ws, size_t ws_size,
                              hipStream_t stream) {
    const float* h0   = (const float*)d_in[0];
    const float* e    = (const float*)d_in[1];
    const int*   src  = (const int*)d_in[2];
    const int*   dst  = (const int*)d_in[3];
    const float* cond = (const float*)d_in[4];
    const float* UW   = (const float*)d_in[5];
    const float* Ub   = (const float*)d_in[6];
    const float* Wih  = (const float*)d_in[7];
    const float* Whh  = (const float*)d_in[8];
    const float* bih  = (const float*)d_in[9];
    const float* bhh  = (const float*)d_in[10];

    const int N = in_sizes[0] / D_NODE;
    const int E = in_sizes[2];
    const int NB = (N + 1023) / 1024;   // scan blocks (<= 256)
    const int NT = (N + ROWS_BLK - 1) / ROWS_BLK;

    char* wsb = (char*)d_ws;
    size_t off = 0;
    auto carve = [&](size_t bytes) -> char* {
        char* p = wsb + off;
        off = (off + bytes + 255) & ~(size_t)255;
        return p;
    };
    int*   cnt      = (int*)carve((size_t)N * 4);
    int*   row_ptr  = (int*)carve(((size_t)N + 1) * 4);
    int*   cursor   = (int*)carve((size_t)N * 4);
    int*   csr_src  = (int*)carve((size_t)E * 4);
    int*   csr_eid  = (int*)carve((size_t)E * 4);
    int*   blk_sums = (int*)carve(256 * 4);
    float* cvec     = (float*)carve(3 * D_NODE * 4);
    _Float16* S_e  = (_Float16*)carve((size_t)N * D_EDGE * 2);
    _Float16* S_h  = (_Float16*)carve((size_t)N * D_NODE * 2);
    _Float16* aggb = (_Float16*)carve((size_t)N * D_NODE * 2);
    _Float16* UWp  = (_Float16*)carve((size_t)3 * D_NODE * 320 * 2);
    _Float16* Wihh = (_Float16*)carve((size_t)3 * GRU3 * D_NODE * 2);
    _Float16* Whhh = (_Float16*)carve((size_t)3 * GRU3 * D_NODE * 2);
    (void)ws_size; (void)n_in; (void)out_size;

    hipMemsetAsync(cnt, 0, (size_t)N * 4, stream);
    hist_k<<<(E + 255) / 256, 256, 0, stream>>>(dst, cnt, E);
    scan1_k<<<NB, 256, 0, stream>>>(cnt, row_ptr, blk_sums, N);
    scan2_k<<<1, 256, 0, stream>>>(blk_sums, NB, row_ptr, N, E);
    scan3_k<<<NB, 256, 0, stream>>>(row_ptr, cursor, blk_sums, N);
    scatter_k<<<(E + 255) / 256, 256, 0, stream>>>(src, dst, cursor, csr_src, csr_eid, E);
    compute_c_k<<<1, 384, 0, stream>>>(UW, Ub, cond, cvec);
    cvt_uwp_k<<<3 * D_NODE, 320, 0, stream>>>(UW, UWp);
    {
        const int n1 = 3 * GRU3 * D_NODE;
        cvt_f32_k<<<(n1 + 255) / 256, 256, 0, stream>>>(Wih, Wihh, n1);
        cvt_f32_k<<<(n1 + 255) / 256, 256, 0, stream>>>(Whh, Whhh, n1);
    }
    gather_e_k<<<(N + 3) / 4, 256, 0, stream>>>(e, row_ptr, csr_eid, S_e, N);

    float* hout = (float*)d_out;
    const float* hc = h0;
    for (int k = 0; k < 3; ++k) {
        gather_h_k<<<(N + 3) / 4, 256, 0, stream>>>(hc, row_ptr, csr_src, S_h, N);
        agg_k<<<NT, 256, 0, stream>>>(
            hc, S_h, S_e, row_ptr, cvec + k * D_NODE,
            UWp + (size_t)k * D_NODE * 320, aggb, N);
        gru_k<<<NT, 256, 0, stream>>>(
            hc, aggb,
            Wihh + (size_t)k * GRU3 * D_NODE,
            Whhh + (size_t)k * GRU3 * D_NODE,
            bih + (size_t)k * GRU3,
            bhh + (size_t)k * GRU3,
            hout, N);   // in-place safe: each block reads/writes only its own rows
        hc = hout;
    }
}

// Round 8
// 575.394 us; speedup vs baseline: 1.9053x; 1.1015x over previous
//
#include <hip/hip_runtime.h>
#include <hip/hip_bf16.h>
#include <hip/hip_fp16.h>

// GGM encode, decomposed (inputs/outputs fp32; internal MFMA in fp16, fp32 accum):
//   agg[v] = deg(v)*(U1 h_v + c_k) + U2*S_h[v] + U3*S_e[v]
//   GRU: gi = agg@Wih^T + bih, gh = h@Whh^T + bhh, fused elementwise in fp32.
// R7->R8: persistent fp16 mirror h16 of h. gru_k writes it alongside fp32 h';
// gather_h reads 256B fp16 rows (halves scattered traffic), agg/gru read a_h
// fragments from h16 (bitwise-identical to cvt8(fp32)). Unroll-2 edge loops for ILP.

#define D_NODE 128
#define D_EDGE 64
#define D_IN   322
#define GRU3   384
#define ROWS_BLK 128
#define PA_STRIDE 328   // panel-A row stride (elems): 656B = 16 mod 128 -> conflict-free
#define PB_STRIDE 136   // panel-B row stride (elems): 272B = 16 mod 128 -> conflict-free

typedef _Float16 f16x8 __attribute__((ext_vector_type(8)));
typedef _Float16 f16x4 __attribute__((ext_vector_type(4)));
typedef _Float16 f16x2 __attribute__((ext_vector_type(2)));
typedef float    f32x4 __attribute__((ext_vector_type(4)));
typedef unsigned short u16x8 __attribute__((ext_vector_type(8)));

__device__ __forceinline__ f16x8 as_f16x8(u16x8 v) { return __builtin_bit_cast(f16x8, v); }
__device__ __forceinline__ float sigm_(float x) { return 1.f / (1.f + __expf(-x)); }
__device__ __forceinline__ float tanh_(float x) { return 1.f - 2.f / (__expf(2.f * x) + 1.f); }

// ---------------- CSR build ----------------
__global__ void hist_k(const int* __restrict__ dst, int* __restrict__ cnt, int E) {
    int t = blockIdx.x * 256 + threadIdx.x;
    if (t < E) atomicAdd(&cnt[dst[t]], 1);
}

__global__ __launch_bounds__(256) void scan1_k(const int* __restrict__ cnt, int* __restrict__ row_ptr,
                                               int* __restrict__ blk_sums, int N) {
    __shared__ int s[256];
    const int t = threadIdx.x;
    const int base = blockIdx.x * 1024 + t * 4;
    int v0 = (base + 0 < N) ? cnt[base + 0] : 0;
    int v1 = (base + 1 < N) ? cnt[base + 1] : 0;
    int v2 = (base + 2 < N) ? cnt[base + 2] : 0;
    int v3 = (base + 3 < N) ? cnt[base + 3] : 0;
    const int tot = v0 + v1 + v2 + v3;
    s[t] = tot;
    __syncthreads();
    for (int off = 1; off < 256; off <<= 1) {
        int u = (t >= off) ? s[t - off] : 0;
        __syncthreads();
        s[t] += u;
        __syncthreads();
    }
    const int excl = s[t] - tot;
    if (base + 0 < N) row_ptr[base + 0] = excl;
    if (base + 1 < N) row_ptr[base + 1] = excl + v0;
    if (base + 2 < N) row_ptr[base + 2] = excl + v0 + v1;
    if (base + 3 < N) row_ptr[base + 3] = excl + v0 + v1 + v2;
    if (t == 255) blk_sums[blockIdx.x] = s[255];
}

__global__ __launch_bounds__(256) void scan2_k(int* __restrict__ blk_sums, int NB,
                                               int* __restrict__ row_ptr, int N, int E) {
    __shared__ int s[256];
    const int t = threadIdx.x;
    const int v = (t < NB) ? blk_sums[t] : 0;
    s[t] = v;
    __syncthreads();
    for (int off = 1; off < 256; off <<= 1) {
        int u = (t >= off) ? s[t - off] : 0;
        __syncthreads();
        s[t] += u;
        __syncthreads();
    }
    if (t < NB) blk_sums[t] = s[t] - v;
    if (t == 0) row_ptr[N] = E;
}

__global__ __launch_bounds__(256) void scan3_k(int* __restrict__ row_ptr, int* __restrict__ cursor,
                                               const int* __restrict__ blk_sums, int N) {
    const int off = blk_sums[blockIdx.x];
    const int base = blockIdx.x * 1024 + threadIdx.x * 4;
#pragma unroll
    for (int j = 0; j < 4; ++j) {
        const int i = base + j;
        if (i < N) {
            const int v = row_ptr[i] + off;
            row_ptr[i] = v;
            cursor[i] = v;
        }
    }
}

__global__ void scatter_k(const int* __restrict__ src, const int* __restrict__ dst,
                          int* __restrict__ cursor, int* __restrict__ csr_src,
                          int* __restrict__ csr_eid, int E) {
    int t = blockIdx.x * 256 + threadIdx.x;
    if (t < E) {
        int d = dst[t];
        int pos = atomicAdd(&cursor[d], 1);
        csr_src[pos] = src[t];
        csr_eid[pos] = t;
    }
}

// ---------------- converts (fp32 -> fp16, once per launch) ----------------
__global__ __launch_bounds__(320) void cvt_uwp_k(const float* __restrict__ in, _Float16* __restrict__ out) {
    const int row = blockIdx.x;   // 0..383
    const int t = threadIdx.x;    // 0..319
    out[(size_t)row * 320 + t] = (_Float16)in[(size_t)row * D_IN + t];
}

__global__ void cvt_f32_k(const float* __restrict__ in, _Float16* __restrict__ out, int n) {
    int t = blockIdx.x * 256 + threadIdx.x;
    if (t < n) out[t] = (_Float16)in[t];
}

__global__ void cvt4_k(const float* __restrict__ in, _Float16* __restrict__ out, int n4) {
    int t = blockIdx.x * 256 + threadIdx.x;
    if (t < n4) {
        const f32x4 v = ((const f32x4*)in)[t];
        f16x4 r;
        r[0] = (_Float16)v[0]; r[1] = (_Float16)v[1];
        r[2] = (_Float16)v[2]; r[3] = (_Float16)v[3];
        ((f16x4*)out)[t] = r;
    }
}

// ---------------- c_k = U4*cond + U_b (fp32 exact) ----------------
__global__ void compute_c_k(const float* __restrict__ UW, const float* __restrict__ Ub,
                            const float* __restrict__ cond, float* __restrict__ cvec) {
    int t = threadIdx.x;
    if (t < 3 * D_NODE) {
        int k = t >> 7, i = t & 127;
        const float* u = UW + (size_t)k * D_NODE * D_IN + (size_t)i * D_IN + 320;
        cvec[t] = u[0] * cond[0] + u[1] * cond[1] + Ub[k * D_NODE + i];
    }
}

// ---------------- segment sums (CSR gather, wave per node; fp32 acc -> fp16) ----------------
__global__ __launch_bounds__(256) void gather_e_k(const float* __restrict__ e,
                                                  const int* __restrict__ row_ptr,
                                                  const int* __restrict__ csr_eid,
                                                  _Float16* __restrict__ S_e, int N) {
    const int wave = threadIdx.x >> 6, lane = threadIdx.x & 63;
    const int n = blockIdx.x * 4 + wave;
    if (n >= N) return;
    const int p0 = row_ptr[n], p1 = row_ptr[n + 1];
    float a = 0.f, b = 0.f;
    int p = p0;
    for (; p + 1 < p1; p += 2) {          // 2 independent row loads in flight
        const int e0 = csr_eid[p], e1 = csr_eid[p + 1];
        a += e[(size_t)e0 * D_EDGE + lane];
        b += e[(size_t)e1 * D_EDGE + lane];
    }
    if (p < p1) a += e[(size_t)csr_eid[p] * D_EDGE + lane];
    S_e[(size_t)n * D_EDGE + lane] = (_Float16)(a + b);
}

// fp16 h rows: 256B/row, one u32 (2 cols) per lane; unroll-2 for ILP.
__global__ __launch_bounds__(256) void gather_h_k(const _Float16* __restrict__ h16,
                                                  const int* __restrict__ row_ptr,
                                                  const int* __restrict__ csr_src,
                                                  _Float16* __restrict__ S_h, int N) {
    const int wave = threadIdx.x >> 6, lane = threadIdx.x & 63;
    const int n = blockIdx.x * 4 + wave;
    if (n >= N) return;
    const unsigned* hp = (const unsigned*)h16;   // 64 u32 per row
    const int p0 = row_ptr[n], p1 = row_ptr[n + 1];
    float a0 = 0.f, a1 = 0.f, b0 = 0.f, b1 = 0.f;
    int p = p0;
    for (; p + 1 < p1; p += 2) {
        const int s0 = csr_src[p], s1 = csr_src[p + 1];
        const f16x2 v0 = __builtin_bit_cast(f16x2, hp[(size_t)s0 * 64 + lane]);
        const f16x2 v1 = __builtin_bit_cast(f16x2, hp[(size_t)s1 * 64 + lane]);
        a0 += (float)v0[0]; a1 += (float)v0[1];
        b0 += (float)v1[0]; b1 += (float)v1[1];
    }
    if (p < p1) {
        const f16x2 v = __builtin_bit_cast(f16x2, hp[(size_t)csr_src[p] * 64 + lane]);
        a0 += (float)v[0]; a1 += (float)v[1];
    }
    f16x2 r;
    r[0] = (_Float16)(a0 + b0);
    r[1] = (_Float16)(a1 + b1);
    ((unsigned*)S_h)[(size_t)n * 64 + lane] = __builtin_bit_cast(unsigned, r);
}

// ---------------- agg kernel: agg = deg*(U1 h + c) + U2 S_h + U3 S_e ----------------
__global__ __launch_bounds__(256) void agg_k(
    const _Float16* __restrict__ h16,
    const _Float16* __restrict__ S_h,
    const _Float16* __restrict__ S_e,
    const int* __restrict__ row_ptr,
    const float* __restrict__ cvec,
    const _Float16* __restrict__ UWp,   // [128][320] fp16, this round's slice
    _Float16* __restrict__ agg,
    int N) {
    __shared__ __align__(16) _Float16 pbuf[2][16 * PA_STRIDE];  // 2 x 10.5 KB

    const int tid  = threadIdx.x;
    const int wave = tid >> 6;
    const int lane = tid & 63;
    const int l15  = lane & 15;
    const int lg   = lane >> 4;
    const int rbase = blockIdx.x * ROWS_BLK + wave * 32;

    const unsigned short* hp  = (const unsigned short*)h16;
    const unsigned short* shp = (const unsigned short*)S_h;
    const unsigned short* sep = (const unsigned short*)S_e;
    const unsigned short* uwp = (const unsigned short*)UWp;

    // A-fragments in registers
    f16x8 a_h[2][4], a_sh[2][4], a_se[2][2];
#pragma unroll
    for (int m = 0; m < 2; ++m) {
        const int arow = min(rbase + m * 16 + l15, N - 1);
#pragma unroll
        for (int kb = 0; kb < 4; ++kb) {
            a_h[m][kb]  = as_f16x8(*(const u16x8*)(hp  + (size_t)arow * D_NODE + kb * 32 + lg * 8));
            a_sh[m][kb] = as_f16x8(*(const u16x8*)(shp + (size_t)arow * D_NODE + kb * 32 + lg * 8));
        }
#pragma unroll
        for (int kb = 0; kb < 2; ++kb)
            a_se[m][kb] = as_f16x8(*(const u16x8*)(sep + (size_t)arow * D_EDGE + kb * 32 + lg * 8));
    }
    float degv[2][4];
#pragma unroll
    for (int m = 0; m < 2; ++m)
#pragma unroll
        for (int i = 0; i < 4; ++i) {
            const int n = min(rbase + m * 16 + lg * 4 + i, N - 1);
            degv[m][i] = (float)(row_ptr[n + 1] - row_ptr[n]);
        }

    // panel staging (reg round-trip; 640 16B-chunks per panel, 3 rounds of 256 thr)
    u16x8 pr0, pr1, pr2;
    auto load_panel = [&](int nb) {
        const int c0 = tid, c1 = 256 + tid, c2 = 512 + tid;
        pr0 = *(const u16x8*)(uwp + (size_t)(nb * 16 + c0 / 40) * 320 + (c0 % 40) * 8);
        pr1 = *(const u16x8*)(uwp + (size_t)(nb * 16 + c1 / 40) * 320 + (c1 % 40) * 8);
        if (c2 < 640)
            pr2 = *(const u16x8*)(uwp + (size_t)(nb * 16 + c2 / 40) * 320 + (c2 % 40) * 8);
    };
    auto write_panel = [&](int b) {
        const int c0 = tid, c1 = 256 + tid, c2 = 512 + tid;
        *(u16x8*)&pbuf[b][(c0 / 40) * PA_STRIDE + (c0 % 40) * 8] = pr0;
        *(u16x8*)&pbuf[b][(c1 / 40) * PA_STRIDE + (c1 % 40) * 8] = pr1;
        if (c2 < 640)
            *(u16x8*)&pbuf[b][(c2 / 40) * PA_STRIDE + (c2 % 40) * 8] = pr2;
    };

    load_panel(0);
    write_panel(0);
    __syncthreads();

#pragma unroll 1
    for (int nb = 0; nb < 8; ++nb) {
        if (nb < 7) load_panel(nb + 1);            // issue early, consume after compute
        const _Float16* bp = pbuf[nb & 1];
        f32x4 acc1[2] = {{0.f,0.f,0.f,0.f},{0.f,0.f,0.f,0.f}};
        f32x4 acc2[2] = {{0.f,0.f,0.f,0.f},{0.f,0.f,0.f,0.f}};
#pragma unroll
        for (int kb = 0; kb < 10; ++kb) {
            f16x8 b = as_f16x8(*(const u16x8*)&bp[l15 * PA_STRIDE + kb * 32 + lg * 8]);
            if (kb < 4) {
                acc1[0] = __builtin_amdgcn_mfma_f32_16x16x32_f16(a_h[0][kb], b, acc1[0], 0, 0, 0);
                acc1[1] = __builtin_amdgcn_mfma_f32_16x16x32_f16(a_h[1][kb], b, acc1[1], 0, 0, 0);
            } else if (kb < 8) {
                acc2[0] = __builtin_amdgcn_mfma_f32_16x16x32_f16(a_sh[0][kb-4], b, acc2[0], 0, 0, 0);
                acc2[1] = __builtin_amdgcn_mfma_f32_16x16x32_f16(a_sh[1][kb-4], b, acc2[1], 0, 0, 0);
            } else {
                acc2[0] = __builtin_amdgcn_mfma_f32_16x16x32_f16(a_se[0][kb-8], b, acc2[0], 0, 0, 0);
                acc2[1] = __builtin_amdgcn_mfma_f32_16x16x32_f16(a_se[1][kb-8], b, acc2[1], 0, 0, 0);
            }
        }
        const float cv = cvec[nb * 16 + l15];
#pragma unroll
        for (int m = 0; m < 2; ++m)
#pragma unroll
            for (int i = 0; i < 4; ++i) {
                const int n = rbase + m * 16 + lg * 4 + i;
                if (n < N)
                    agg[(size_t)n * D_NODE + nb * 16 + l15] =
                        (_Float16)(degv[m][i] * (acc1[m][i] + cv) + acc2[m][i]);
            }
        if (nb < 7) write_panel((nb + 1) & 1);
        __syncthreads();
    }
}

// ---------------- GRU kernel: h' = (1-z)*n + z*h ; also emits h16 mirror ----------------
__global__ __launch_bounds__(256) void gru_k(
    const float* __restrict__ h_cur,
    _Float16* __restrict__ h16,          // read a_h fragments; write fp16(h') in-place
    const _Float16* __restrict__ agg,
    const _Float16* __restrict__ Wihh,  // [384][128] fp16
    const _Float16* __restrict__ Whhh,  // [384][128] fp16
    const float* __restrict__ bih,
    const float* __restrict__ bhh,
    float* __restrict__ h_next,
    int N) {
    __shared__ __align__(16) _Float16 pbuf[2][96 * PB_STRIDE];  // 2 x 25.5 KB

    const int tid  = threadIdx.x;
    const int wave = tid >> 6;
    const int lane = tid & 63;
    const int l15  = lane & 15;
    const int lg   = lane >> 4;
    const int rbase = blockIdx.x * ROWS_BLK + wave * 32;

    const unsigned short* hp  = (const unsigned short*)h16;
    const unsigned short* agp = (const unsigned short*)agg;
    const unsigned short* wih = (const unsigned short*)Wihh;
    const unsigned short* whh = (const unsigned short*)Whhh;

    f16x8 a_ag[2][4], a_h[2][4];
#pragma unroll
    for (int m = 0; m < 2; ++m) {
        const int arow = min(rbase + m * 16 + l15, N - 1);
#pragma unroll
        for (int kb = 0; kb < 4; ++kb) {
            a_ag[m][kb] = as_f16x8(*(const u16x8*)(agp + (size_t)arow * D_NODE + kb * 32 + lg * 8));
            a_h[m][kb]  = as_f16x8(*(const u16x8*)(hp  + (size_t)arow * D_NODE + kb * 32 + lg * 8));
        }
    }

    // panel staging: 1536 16B-chunks = 6 rounds x 256 thr
    u16x8 pr[6];
    auto load_panel = [&](int nb) {
#pragma unroll
        for (int r = 0; r < 6; ++r) {
            const int c = r * 256 + tid;
            const int row = c >> 4;            // 0..95
            const int off = (c & 15) * 8;      // elems
            const int gate = row >> 4;         // 0..5
            const int col = nb * 16 + (row & 15) + (gate % 3) * D_NODE;
            const unsigned short* mat = (gate < 3) ? wih : whh;
            pr[r] = *(const u16x8*)(mat + (size_t)col * D_NODE + off);
        }
    };
    auto write_panel = [&](int b) {
#pragma unroll
        for (int r = 0; r < 6; ++r) {
            const int c = r * 256 + tid;
            const int row = c >> 4;
            const int off = (c & 15) * 8;
            *(u16x8*)&pbuf[b][row * PB_STRIDE + off] = pr[r];
        }
    };

    load_panel(0);
    write_panel(0);
    __syncthreads();

#pragma unroll 1
    for (int nb = 0; nb < 8; ++nb) {
        if (nb < 7) load_panel(nb + 1);
        const int d = nb * 16 + l15;
        float hv[2][4];
#pragma unroll
        for (int m = 0; m < 2; ++m)
#pragma unroll
            for (int i = 0; i < 4; ++i) {
                const int n = min(rbase + m * 16 + lg * 4 + i, N - 1);
                hv[m][i] = h_cur[(size_t)n * D_NODE + d];
            }
        const float bir = bih[d],       biz = bih[128 + d], bin = bih[256 + d];
        const float bhr = bhh[d],       bhz = bhh[128 + d], bhn = bhh[256 + d];

        const _Float16* bp = pbuf[nb & 1];
        f32x4 air[2] = {{0.f,0.f,0.f,0.f},{0.f,0.f,0.f,0.f}};
        f32x4 aiz[2] = {{0.f,0.f,0.f,0.f},{0.f,0.f,0.f,0.f}};
        f32x4 ain_[2] = {{0.f,0.f,0.f,0.f},{0.f,0.f,0.f,0.f}};
        f32x4 ahr[2] = {{0.f,0.f,0.f,0.f},{0.f,0.f,0.f,0.f}};
        f32x4 ahz[2] = {{0.f,0.f,0.f,0.f},{0.f,0.f,0.f,0.f}};
        f32x4 ahn[2] = {{0.f,0.f,0.f,0.f},{0.f,0.f,0.f,0.f}};
#pragma unroll
        for (int kb = 0; kb < 4; ++kb) {
            const int ko = kb * 32 + lg * 8;
            f16x8 b;
            b = as_f16x8(*(const u16x8*)&bp[(0 * 16 + l15) * PB_STRIDE + ko]);
            air[0] = __builtin_amdgcn_mfma_f32_16x16x32_f16(a_ag[0][kb], b, air[0], 0, 0, 0);
            air[1] = __builtin_amdgcn_mfma_f32_16x16x32_f16(a_ag[1][kb], b, air[1], 0, 0, 0);
            b = as_f16x8(*(const u16x8*)&bp[(1 * 16 + l15) * PB_STRIDE + ko]);
            aiz[0] = __builtin_amdgcn_mfma_f32_16x16x32_f16(a_ag[0][kb], b, aiz[0], 0, 0, 0);
            aiz[1] = __builtin_amdgcn_mfma_f32_16x16x32_f16(a_ag[1][kb], b, aiz[1], 0, 0, 0);
            b = as_f16x8(*(const u16x8*)&bp[(2 * 16 + l15) * PB_STRIDE + ko]);
            ain_[0] = __builtin_amdgcn_mfma_f32_16x16x32_f16(a_ag[0][kb], b, ain_[0], 0, 0, 0);
            ain_[1] = __builtin_amdgcn_mfma_f32_16x16x32_f16(a_ag[1][kb], b, ain_[1], 0, 0, 0);
            b = as_f16x8(*(const u16x8*)&bp[(3 * 16 + l15) * PB_STRIDE + ko]);
            ahr[0] = __builtin_amdgcn_mfma_f32_16x16x32_f16(a_h[0][kb], b, ahr[0], 0, 0, 0);
            ahr[1] = __builtin_amdgcn_mfma_f32_16x16x32_f16(a_h[1][kb], b, ahr[1], 0, 0, 0);
            b = as_f16x8(*(const u16x8*)&bp[(4 * 16 + l15) * PB_STRIDE + ko]);
            ahz[0] = __builtin_amdgcn_mfma_f32_16x16x32_f16(a_h[0][kb], b, ahz[0], 0, 0, 0);
            ahz[1] = __builtin_amdgcn_mfma_f32_16x16x32_f16(a_h[1][kb], b, ahz[1], 0, 0, 0);
            b = as_f16x8(*(const u16x8*)&bp[(5 * 16 + l15) * PB_STRIDE + ko]);
            ahn[0] = __builtin_amdgcn_mfma_f32_16x16x32_f16(a_h[0][kb], b, ahn[0], 0, 0, 0);
            ahn[1] = __builtin_amdgcn_mfma_f32_16x16x32_f16(a_h[1][kb], b, ahn[1], 0, 0, 0);
        }
#pragma unroll
        for (int m = 0; m < 2; ++m)
#pragma unroll
            for (int i = 0; i < 4; ++i) {
                const int n = rbase + m * 16 + lg * 4 + i;
                if (n < N) {
                    const float r  = sigm_(air[m][i] + bir + ahr[m][i] + bhr);
                    const float z  = sigm_(aiz[m][i] + biz + ahz[m][i] + bhz);
                    const float nn = tanh_(ain_[m][i] + bin + r * (ahn[m][i] + bhn));
                    const float hval = (1.f - z) * nn + z * hv[m][i];
                    h_next[(size_t)n * D_NODE + d] = hval;
                    h16[(size_t)n * D_NODE + d] = (_Float16)hval;  // mirror for next round
                }
            }
        if (nb < 7) write_panel((nb + 1) & 1);
        __syncthreads();
    }
}

// ---------------- launch ----------------
extern "C" void kernel_launch(void* const* d_in, const int* in_sizes, int n_in,
                              void* d_out, int out_size, void* d_ws, size_t ws_size,
                              hipStream_t stream) {
    const float* h0   = (const float*)d_in[0];
    const float* e    = (const float*)d_in[1];
    const int*   src  = (const int*)d_in[2];
    const int*   dst  = (const int*)d_in[3];
    const float* cond = (const float*)d_in[4];
    const float* UW   = (const float*)d_in[5];
    const float* Ub   = (const float*)d_in[6];
    const float* Wih  = (const float*)d_in[7];
    const float* Whh  = (const float*)d_in[8];
    const float* bih  = (const float*)d_in[9];
    const float* bhh  = (const float*)d_in[10];

    const int N = in_sizes[0] / D_NODE;
    const int E = in_sizes[2];
    const int NB = (N + 1023) / 1024;   // scan blocks (<= 256)
    const int NT = (N + ROWS_BLK - 1) / ROWS_BLK;

    char* wsb = (char*)d_ws;
    size_t off = 0;
    auto carve = [&](size_t bytes) -> char* {
        char* p = wsb + off;
        off = (off + bytes + 255) & ~(size_t)255;
        return p;
    };
    int*   cnt      = (int*)carve((size_t)N * 4);
    int*   row_ptr  = (int*)carve(((size_t)N + 1) * 4);
    int*   cursor   = (int*)carve((size_t)N * 4);
    int*   csr_src  = (int*)carve((size_t)E * 4);
    int*   csr_eid  = (int*)carve((size_t)E * 4);
    int*   blk_sums = (int*)carve(256 * 4);
    float* cvec     = (float*)carve(3 * D_NODE * 4);
    _Float16* S_e  = (_Float16*)carve((size_t)N * D_EDGE * 2);
    _Float16* S_h  = (_Float16*)carve((size_t)N * D_NODE * 2);
    _Float16* aggb = (_Float16*)carve((size_t)N * D_NODE * 2);
    _Float16* h16  = (_Float16*)carve((size_t)N * D_NODE * 2);
    _Float16* UWp  = (_Float16*)carve((size_t)3 * D_NODE * 320 * 2);
    _Float16* Wihh = (_Float16*)carve((size_t)3 * GRU3 * D_NODE * 2);
    _Float16* Whhh = (_Float16*)carve((size_t)3 * GRU3 * D_NODE * 2);
    (void)ws_size; (void)n_in; (void)out_size;

    hipMemsetAsync(cnt, 0, (size_t)N * 4, stream);
    hist_k<<<(E + 255) / 256, 256, 0, stream>>>(dst, cnt, E);
    scan1_k<<<NB, 256, 0, stream>>>(cnt, row_ptr, blk_sums, N);
    scan2_k<<<1, 256, 0, stream>>>(blk_sums, NB, row_ptr, N, E);
    scan3_k<<<NB, 256, 0, stream>>>(row_ptr, cursor, blk_sums, N);
    scatter_k<<<(E + 255) / 256, 256, 0, stream>>>(src, dst, cursor, csr_src, csr_eid, E);
    compute_c_k<<<1, 384, 0, stream>>>(UW, Ub, cond, cvec);
    cvt_uwp_k<<<3 * D_NODE, 320, 0, stream>>>(UW, UWp);
    {
        const int n1 = 3 * GRU3 * D_NODE;
        cvt_f32_k<<<(n1 + 255) / 256, 256, 0, stream>>>(Wih, Wihh, n1);
        cvt_f32_k<<<(n1 + 255) / 256, 256, 0, stream>>>(Whh, Whhh, n1);
    }
    {
        const int n4 = N * D_NODE / 4;
        cvt4_k<<<(n4 + 255) / 256, 256, 0, stream>>>(h0, h16, n4);   // seed fp16 mirror
    }
    gather_e_k<<<(N + 3) / 4, 256, 0, stream>>>(e, row_ptr, csr_eid, S_e, N);

    float* hout = (float*)d_out;
    const float* hc = h0;
    for (int k = 0; k < 3; ++k) {
        gather_h_k<<<(N + 3) / 4, 256, 0, stream>>>(h16, row_ptr, csr_src, S_h, N);
        agg_k<<<NT, 256, 0, stream>>>(
            h16, S_h, S_e, row_ptr, cvec + k * D_NODE,
            UWp + (size_t)k * D_NODE * 320, aggb, N);
        gru_k<<<NT, 256, 0, stream>>>(
            hc, h16, aggb,
            Wihh + (size_t)k * GRU3 * D_NODE,
            Whhh + (size_t)k * GRU3 * D_NODE,
            bih + (size_t)k * GRU3,
            bhh + (size_t)k * GRU3,
            hout, N);   // in-place safe: each block reads/writes only its own rows
        hc = hout;
    }
}